// Round 4
// baseline (26519.348 us; speedup 1.0000x reference)
//
#include <hip/hip_runtime.h>

typedef unsigned short u16;
typedef unsigned int   u32;

#define NTHREADS 512
#define NBLOCKS  256
#define BB       2
#define STEPS    1024
#define TPTS     1025
#define HDIM     64
#define NZ       16
#define WID      128
#define IND      65
#define HN       1024

__device__ __forceinline__ float bf2f(u16 v) { return __uint_as_float(((u32)v) << 16); }
__device__ __forceinline__ u16 f2bf(float f) {
    u32 u = __float_as_uint(f);
    return (u16)((u + 0x7fffu + ((u >> 16) & 1u)) >> 16);
}
__device__ __forceinline__ float lo16(u32 u) { return __uint_as_float(u << 16); }
__device__ __forceinline__ float hi16(u32 u) { return __uint_as_float(u & 0xffff0000u); }
__device__ __forceinline__ u32 pk(float a, float b) {
    return (u32)f2bf(a) | ((u32)f2bf(b) << 16);
}

// runtime-dtype loads: is32 ? fp32 buffer : bf16 buffer
__device__ __forceinline__ float ldf(const void* p, int i, bool is32) {
    return is32 ? ((const float*)p)[i] : bf2f(((const u16*)p)[i]);
}
__device__ __forceinline__ u16 ldbf(const void* p, int i, bool is32) {
    return is32 ? f2bf(((const float*)p)[i]) : ((const u16*)p)[i];
}

__device__ __forceinline__ float lipswish(float x) {
    return 0.909f * x / (1.0f + __expf(-x));
}
__device__ __forceinline__ float tanh_fast(float x) {
    float e = __expf(2.0f * fabsf(x));   // may be +inf -> t = 1
    float t = 1.0f - 2.0f / (e + 1.0f);
    return copysignf(t, x);
}

struct __align__(16) SMem {
    u32 vW0p[WID][33];    // pairs of bf16 along K (65 -> 33 pairs, last hi=0)
    u32 cW0p[WID][33];
    u32 vW1p[WID][65];    // 64 pairs + 1 pad column
    u32 cW1p[WID][65];
    u32 vW2p[HDIM][65];
    float vb0[WID], vb1[WID], vb2[HDIM], vsc[HDIM];
    float cb0[WID], cb1[WID];
    float cb2[HN];
    float csc[HN];
    float roW[8][HDIM];
    float rob[8];
    float tsb[1028];
    float x[BB][68];      // [t, y(64), 0pad]; stride 68 keeps rows 16B-aligned
    float h1[2][BB][WID];
    float h2[2][BB][WID];
    float yb[BB][HDIM];
    float fdt[BB][HDIM];
    float g0b[BB][HDIM];
    float gs[BB][HDIM];
    float dwb[BB][NZ];
};

__device__ __forceinline__ float dot64p(const u32* __restrict__ Wp, const float2* __restrict__ xp) {
    float a0 = 0.f, a1 = 0.f, a2 = 0.f, a3 = 0.f;
    #pragma unroll
    for (int kk = 0; kk < 64; kk += 4) {
        u32 w0 = Wp[kk], w1 = Wp[kk+1], w2 = Wp[kk+2], w3 = Wp[kk+3];
        float2 x0 = xp[kk], x1 = xp[kk+1], x2 = xp[kk+2], x3 = xp[kk+3];
        a0 = fmaf(lo16(w0), x0.x, fmaf(hi16(w0), x0.y, a0));
        a1 = fmaf(lo16(w1), x1.x, fmaf(hi16(w1), x1.y, a1));
        a2 = fmaf(lo16(w2), x2.x, fmaf(hi16(w2), x2.y, a2));
        a3 = fmaf(lo16(w3), x3.x, fmaf(hi16(w3), x3.y, a3));
    }
    return (a0 + a1) + (a2 + a3);
}

__device__ __forceinline__ float dot33p(const u32* __restrict__ Wp, const float2* __restrict__ xp) {
    float a0 = 0.f, a1 = 0.f, a2 = 0.f, a3 = 0.f;
    #pragma unroll
    for (int kk = 0; kk < 32; kk += 4) {
        u32 w0 = Wp[kk], w1 = Wp[kk+1], w2 = Wp[kk+2], w3 = Wp[kk+3];
        float2 x0 = xp[kk], x1 = xp[kk+1], x2 = xp[kk+2], x3 = xp[kk+3];
        a0 = fmaf(lo16(w0), x0.x, fmaf(hi16(w0), x0.y, a0));
        a1 = fmaf(lo16(w1), x1.x, fmaf(hi16(w1), x1.y, a1));
        a2 = fmaf(lo16(w2), x2.x, fmaf(hi16(w2), x2.y, a2));
        a3 = fmaf(lo16(w3), x3.x, fmaf(hi16(w3), x3.y, a3));
    }
    u32 wl = Wp[32]; float2 xv = xp[32];
    a0 = fmaf(lo16(wl), xv.x, fmaf(hi16(wl), xv.y, a0));
    return (a0 + a1) + (a2 + a3);
}

// function, not macro (Round 1: macro param 'w' collided with member '.w')
__device__ __forceinline__ void bigrow(float& acc, const uint4& wv, const float4& pv, const float4& qv) {
    acc = fmaf(lo16(wv.x), pv.x, acc);
    acc = fmaf(hi16(wv.x), pv.y, acc);
    acc = fmaf(lo16(wv.y), pv.z, acc);
    acc = fmaf(hi16(wv.y), pv.w, acc);
    acc = fmaf(lo16(wv.z), qv.x, acc);
    acc = fmaf(hi16(wv.z), qv.y, acc);
    acc = fmaf(lo16(wv.w), qv.z, acc);
    acc = fmaf(hi16(wv.w), qv.w, acc);
}

__device__ __forceinline__ void big_layer(SMem& sm, const uint4 (&wr)[32], int tid) {
    const int r0 = 2 * tid;
    float a00 = sm.cb2[r0], a01 = sm.cb2[r0 + 1];
    float a10 = a00, a11 = a01;
    const float4* hA = (const float4*)sm.h2[1][0];
    const float4* hB = (const float4*)sm.h2[1][1];
    #pragma unroll
    for (int i = 0; i < 16; ++i) {
        uint4 wa = wr[i];
        uint4 wb = wr[16 + i];
        float4 p0 = hA[2*i], q0 = hA[2*i + 1];
        float4 p1 = hB[2*i], q1 = hB[2*i + 1];
        bigrow(a00, wa, p0, q0);
        bigrow(a01, wb, p0, q0);
        bigrow(a10, wa, p1, q1);
        bigrow(a11, wb, p1, q1);
    }
    const float c0 = sm.csc[r0], c1 = sm.csc[r0 + 1];
    const int n0 = r0 & 15;
    float v0 = c0 * tanh_fast(a00) * sm.dwb[0][n0] + c1 * tanh_fast(a01) * sm.dwb[0][n0 + 1];
    float v1 = c0 * tanh_fast(a10) * sm.dwb[1][n0] + c1 * tanh_fast(a11) * sm.dwb[1][n0 + 1];
    #pragma unroll
    for (int m = 1; m < 8; m <<= 1) {
        v0 += __shfl_xor(v0, m);
        v1 += __shfl_xor(v1, m);
    }
    if ((tid & 7) == 0) {
        sm.gs[0][tid >> 3] = v0;
        sm.gs[1][tid >> 3] = v1;
    }
}

__device__ __forceinline__ void stage_dw(SMem& sm, const uint4& d, int q, bool is32, float sdt) {
    if (is32) {
        const float* pf = (const float*)&d;
        int f = q * 4;
        #pragma unroll
        for (int k = 0; k < 4; ++k)
            sm.dwb[(f + k) >> 4][(f + k) & 15] = pf[k] * sdt;
    } else {
        int f = q * 8;
        u32 u0 = d.x, u1 = d.y, u2 = d.z, u3 = d.w;
        sm.dwb[(f    ) >> 4][(f    ) & 15] = lo16(u0) * sdt;
        sm.dwb[(f + 1) >> 4][(f + 1) & 15] = hi16(u0) * sdt;
        sm.dwb[(f + 2) >> 4][(f + 2) & 15] = lo16(u1) * sdt;
        sm.dwb[(f + 3) >> 4][(f + 3) & 15] = hi16(u1) * sdt;
        sm.dwb[(f + 4) >> 4][(f + 4) & 15] = lo16(u2) * sdt;
        sm.dwb[(f + 5) >> 4][(f + 5) & 15] = hi16(u2) * sdt;
        sm.dwb[(f + 6) >> 4][(f + 6) & 15] = lo16(u3) * sdt;
        sm.dwb[(f + 7) >> 4][(f + 7) & 15] = hi16(u3) * sdt;
    }
}

__device__ __forceinline__ void write_out(void* out, bool is32, size_t idx, const float* v8) {
    if (is32) {
        float4 o0, o1;
        o0.x = v8[0]; o0.y = v8[1]; o0.z = v8[2]; o0.w = v8[3];
        o1.x = v8[4]; o1.y = v8[5]; o1.z = v8[6]; o1.w = v8[7];
        ((float4*)out)[idx * 2]     = o0;
        ((float4*)out)[idx * 2 + 1] = o1;
    } else {
        uint4 o;
        o.x = pk(v8[0], v8[1]);
        o.y = pk(v8[2], v8[3]);
        o.z = pk(v8[4], v8[5]);
        o.w = pk(v8[6], v8[7]);
        ((uint4*)out)[idx] = o;
    }
}

// launch_bounds(512, 1): R3 used (512,2) -> compiler capped at 128 VGPR and
// spilled the 128-reg wr[] to scratch (24.7 GB FETCH_SIZE/dispatch, VALUBusy 27%).
// A 512-thread block needs 2 waves/SIMD -> hard VGPR cap 256; (512,1) lets the
// allocator use it and keep wr resident.
__global__ void __launch_bounds__(NTHREADS, 1)
sde_kernel(const void* __restrict__ ts,  const void* __restrict__ z0,  const void* __restrict__ dW,
           const void* __restrict__ iW0, const void* __restrict__ ib0, const void* __restrict__ iW1,
           const void* __restrict__ ib1, const void* __restrict__ iW2, const void* __restrict__ ib2,
           const void* __restrict__ vW0, const void* __restrict__ vb0, const void* __restrict__ vW1,
           const void* __restrict__ vb1, const void* __restrict__ vW2, const void* __restrict__ vb2,
           const void* __restrict__ vsc, const void* __restrict__ cW0, const void* __restrict__ cb0,
           const void* __restrict__ cW1, const void* __restrict__ cb1, const void* __restrict__ cW2,
           const void* __restrict__ cb2, const void* __restrict__ csc, const void* __restrict__ roW,
           const void* __restrict__ rob, void* __restrict__ out)
{
    __shared__ SMem sm;
    const int tid  = threadIdx.x;
    const int bid  = blockIdx.x;

    // dtype detection: u16 word #1 of ts. bf16: bf16(1/1024)=0x3A80 != 0.
    // fp32: high half of 0.0f == 0.
    const bool is32 = (((const u16*)ts)[1] == 0);

    // ---- cW2 rows 2*tid, 2*tid+1 -> registers (bf16-packed either way) ----
    uint4 wr[32];
    if (!is32) {
        const uint4* p0 = (const uint4*)((const u16*)cW2 + (size_t)(2 * tid)     * WID);
        const uint4* p1 = (const uint4*)((const u16*)cW2 + (size_t)(2 * tid + 1) * WID);
        #pragma unroll
        for (int i = 0; i < 16; ++i) wr[i] = p0[i];
        #pragma unroll
        for (int i = 0; i < 16; ++i) wr[16 + i] = p1[i];
    } else {
        const float4* f0 = (const float4*)((const float*)cW2 + (size_t)(2 * tid)     * WID);
        const float4* f1 = (const float4*)((const float*)cW2 + (size_t)(2 * tid + 1) * WID);
        #pragma unroll
        for (int i = 0; i < 16; ++i) {
            float4 a = f0[2*i], b = f0[2*i+1];
            uint4 w; w.x = pk(a.x, a.y); w.y = pk(a.z, a.w); w.z = pk(b.x, b.y); w.w = pk(b.z, b.w);
            wr[i] = w;
        }
        #pragma unroll
        for (int i = 0; i < 16; ++i) {
            float4 a = f1[2*i], b = f1[2*i+1];
            uint4 w; w.x = pk(a.x, a.y); w.y = pk(a.z, a.w); w.z = pk(b.x, b.y); w.w = pk(b.z, b.w);
            wr[16 + i] = w;
        }
    }

    // ---- stage weights into LDS as packed bf16 pairs ----
    for (int idx = tid; idx < WID * 33; idx += NTHREADS) {
        int j = idx / 33, kk = idx - j * 33;
        int k0 = 2 * kk;
        u32 lo, hi;
        lo = ldbf(vW0, j * IND + k0, is32);
        hi = (k0 + 1 < IND) ? (u32)ldbf(vW0, j * IND + k0 + 1, is32) : 0u;
        sm.vW0p[j][kk] = lo | (hi << 16);
        lo = ldbf(cW0, j * IND + k0, is32);
        hi = (k0 + 1 < IND) ? (u32)ldbf(cW0, j * IND + k0 + 1, is32) : 0u;
        sm.cW0p[j][kk] = lo | (hi << 16);
    }
    for (int idx = tid; idx < WID * 65; idx += NTHREADS) {
        int j = idx / 65, kk = idx - j * 65;
        u32 v = 0, c = 0;
        if (kk < 64) {
            int k0 = 2 * kk;
            v = (u32)ldbf(vW1, j * WID + k0, is32) | ((u32)ldbf(vW1, j * WID + k0 + 1, is32) << 16);
            c = (u32)ldbf(cW1, j * WID + k0, is32) | ((u32)ldbf(cW1, j * WID + k0 + 1, is32) << 16);
        }
        sm.vW1p[j][kk] = v;
        sm.cW1p[j][kk] = c;
    }
    for (int idx = tid; idx < HDIM * 65; idx += NTHREADS) {
        int j = idx / 65, kk = idx - j * 65;
        u32 v = 0;
        if (kk < 64) {
            int k0 = 2 * kk;
            v = (u32)ldbf(vW2, j * WID + k0, is32) | ((u32)ldbf(vW2, j * WID + k0 + 1, is32) << 16);
        }
        sm.vW2p[j][kk] = v;
    }
    if (tid < WID) {
        sm.vb0[tid] = ldf(vb0, tid, is32); sm.vb1[tid] = ldf(vb1, tid, is32);
        sm.cb0[tid] = ldf(cb0, tid, is32); sm.cb1[tid] = ldf(cb1, tid, is32);
        if (tid < HDIM) { sm.vb2[tid] = ldf(vb2, tid, is32); sm.vsc[tid] = ldf(vsc, tid, is32); }
        if (tid < 8) sm.rob[tid] = ldf(rob, tid, is32);
    }
    for (int i = tid; i < HN; i += NTHREADS) {
        sm.cb2[i] = ldf(cb2, i, is32);
        sm.csc[i] = ldf(csc, i, is32);
    }
    { int d = tid >> 6, i2 = tid & 63; sm.roW[d][i2] = ldf(roW, tid, is32); }
    for (int i = tid; i < TPTS; i += NTHREADS) sm.tsb[i] = ldf(ts, i, is32);

    // prefetch dW for step 0
    uint4 dwpref;
    if (tid >= 128 && tid < 136) {
        int q = tid - 128;
        if (is32)       dwpref = ((const uint4*)dW)[(size_t)bid * 8 + q];       // 8 x float4
        else if (q < 4) dwpref = ((const uint4*)dW)[(size_t)bid * 4 + q];       // 4 x bf16x8
    }

    __syncthreads();

    const float dt  = sm.tsb[1] - sm.tsb[0];
    const float sdt = sqrtf(dt);

    if (tid >= 128 && tid < 136) {
        int q = tid - 128;
        if (is32 || q < 4) stage_dw(sm, dwpref, q, is32, sdt);
    }

    // ---- initial MLP (relu, relu, identity): z0(8) -> 128 -> 128 -> y0(64) ----
    if (tid < 256) {   // I1
        int b = tid >> 7, j = tid & 127;
        float acc = ldf(ib0, j, is32);
        #pragma unroll
        for (int k = 0; k < 8; ++k)
            acc = fmaf(ldf(iW0, j * 8 + k, is32), ldf(z0, (bid * BB + b) * 8 + k, is32), acc);
        sm.h1[0][b][j] = fmaxf(acc, 0.0f);
    }
    __syncthreads();
    if (tid < 256) {   // I2
        int b = tid >> 7, j = tid & 127;
        float acc = ldf(ib1, j, is32);
        for (int k = 0; k < WID; ++k)
            acc = fmaf(ldf(iW1, j * WID + k, is32), sm.h1[0][b][k], acc);
        sm.h2[0][b][j] = fmaxf(acc, 0.0f);
    }
    __syncthreads();
    if (tid < 128) {   // I3: y0, x init, t=0 readout
        int b = tid >> 6, i = tid & 63;
        float y0 = ldf(ib2, i, is32);
        for (int k = 0; k < WID; ++k)
            y0 = fmaf(ldf(iW2, i * WID + k, is32), sm.h2[0][b][k], y0);
        sm.yb[b][i] = y0;
        sm.x[b][1 + i] = y0;
        if (i == 0) {
            sm.x[b][0] = sm.tsb[0];
            sm.x[b][65] = 0.0f; sm.x[b][66] = 0.0f; sm.x[b][67] = 0.0f;
        }
        float acc[8];
        #pragma unroll
        for (int d = 0; d < 8; ++d) acc[d] = sm.roW[d][i] * y0;
        #pragma unroll
        for (int m = 1; m < 64; m <<= 1) {
            #pragma unroll
            for (int d = 0; d < 8; ++d) acc[d] += __shfl_xor(acc[d], m);
        }
        if (i == 0) {
            float v8[8];
            #pragma unroll
            for (int d = 0; d < 8; ++d) v8[d] = acc[d] + sm.rob[d];
            write_out(out, is32, (size_t)(bid * BB + b) * TPTS, v8);
        }
    }
    __syncthreads();

    // ---- main scan: 1024 Euler-Heun steps ----
    for (int s = 0; s < STEPS; ++s) {
        if (s + 1 < STEPS && tid >= 128 && tid < 136) {
            int q = tid - 128;
            if (is32)       dwpref = ((const uint4*)dW)[(size_t)(s + 1) * 2048 + bid * 8 + q];
            else if (q < 4) dwpref = ((const uint4*)dW)[(size_t)(s + 1) * 1024 + bid * 4 + q];
        }
        // P2: fused L0 for drift(v=0) and diffusion(c=1), input x=[t,y]
        {
            const int mlp = tid >> 8, b = (tid >> 7) & 1, j = tid & 127;
            const u32* Wp = mlp ? sm.cW0p[j] : sm.vW0p[j];
            const float bias = mlp ? sm.cb0[j] : sm.vb0[j];
            float acc = bias + dot33p(Wp, (const float2*)sm.x[b]);
            sm.h1[mlp][b][j] = lipswish(acc);
        }
        __syncthreads();
        // P3: fused L1
        {
            const int mlp = tid >> 8, b = (tid >> 7) & 1, j = tid & 127;
            const u32* Wp = mlp ? sm.cW1p[j] : sm.vW1p[j];
            const float bias = mlp ? sm.cb1[j] : sm.vb1[j];
            float acc = bias + dot64p(Wp, (const float2*)sm.h1[mlp][b]);
            sm.h2[mlp][b][j] = lipswish(acc);
        }
        __syncthreads();
        // P4: diffusion big layer eval 1 -> gs = g0
        big_layer(sm, wr, tid);
        __syncthreads();
        // P5: x' = y + g0 (waves 0-1) | drift L2 -> fdt (waves 2-3)
        if (tid < 128) {
            int b = tid >> 6, i = tid & 63;
            float g0 = sm.gs[b][i];
            sm.g0b[b][i] = g0;
            sm.x[b][1 + i] = sm.yb[b][i] + g0;
        } else if (tid < 256) {
            int q = tid - 128, b = q >> 6, j = q & 63;
            float acc = sm.vb2[j] + dot64p(sm.vW2p[j], (const float2*)sm.h2[0][b]);
            sm.fdt[b][j] = sm.vsc[j] * tanh_fast(acc) * dt;
        }
        __syncthreads();
        // P6: diffusion L0 on x'
        if (tid < 256) {
            int b = tid >> 7, j = tid & 127;
            float acc = sm.cb0[j] + dot33p(sm.cW0p[j], (const float2*)sm.x[b]);
            sm.h1[1][b][j] = lipswish(acc);
        }
        __syncthreads();
        // P7: diffusion L1
        if (tid < 256) {
            int b = tid >> 7, j = tid & 127;
            float acc = sm.cb1[j] + dot64p(sm.cW1p[j], (const float2*)sm.h1[1][b]);
            sm.h2[1][b][j] = lipswish(acc);
        }
        __syncthreads();
        // P8: diffusion big layer eval 2 -> gs = g1
        big_layer(sm, wr, tid);
        __syncthreads();
        // P9: y1 = y + f0*dt + 0.5*(g0+g1); readout; stage next x and dw
        if (tid < 128) {
            int b = tid >> 6, i = tid & 63;
            float y1 = sm.yb[b][i] + sm.fdt[b][i] + 0.5f * (sm.g0b[b][i] + sm.gs[b][i]);
            sm.yb[b][i] = y1;
            sm.x[b][1 + i] = y1;
            if (i == 0) sm.x[b][0] = sm.tsb[s + 1];
            float acc[8];
            #pragma unroll
            for (int d = 0; d < 8; ++d) acc[d] = sm.roW[d][i] * y1;
            #pragma unroll
            for (int m = 1; m < 64; m <<= 1) {
                #pragma unroll
                for (int d = 0; d < 8; ++d) acc[d] += __shfl_xor(acc[d], m);
            }
            if (i == 0) {
                float v8[8];
                #pragma unroll
                for (int d = 0; d < 8; ++d) v8[d] = acc[d] + sm.rob[d];
                write_out(out, is32, (size_t)(bid * BB + b) * TPTS + (s + 1), v8);
            }
        } else if (tid >= 128 && tid < 136 && s + 1 < STEPS) {
            int q = tid - 128;
            if (is32 || q < 4) stage_dw(sm, dwpref, q, is32, sdt);
        }
        __syncthreads();
    }
}

extern "C" void kernel_launch(void* const* d_in, const int* in_sizes, int n_in,
                              void* d_out, int out_size, void* d_ws, size_t ws_size,
                              hipStream_t stream) {
    (void)in_sizes; (void)n_in; (void)d_ws; (void)ws_size; (void)out_size;
    hipLaunchKernelGGL(sde_kernel, dim3(NBLOCKS), dim3(NTHREADS), 0, stream,
                       d_in[0], d_in[1], d_in[2], d_in[3], d_in[4], d_in[5], d_in[6],
                       d_in[7], d_in[8], d_in[9], d_in[10], d_in[11], d_in[12], d_in[13],
                       d_in[14], d_in[15], d_in[16], d_in[17], d_in[18], d_in[19], d_in[20],
                       d_in[21], d_in[22], d_in[23], d_in[24], d_out);
}

// Round 5
// 26350.076 us; speedup vs baseline: 1.0064x; 1.0064x over previous
//
#include <hip/hip_runtime.h>

typedef unsigned short u16;
typedef unsigned int   u32;

#define NTHREADS 512
#define NBLOCKS  256
#define BB       2
#define STEPS    1024
#define TPTS     1025
#define HDIM     64
#define NZ       16
#define WID      128
#define IND      65
#define HN       1024

__device__ __forceinline__ float bf2f(u16 v) { return __uint_as_float(((u32)v) << 16); }
__device__ __forceinline__ u16 f2bf(float f) {
    u32 u = __float_as_uint(f);
    return (u16)((u + 0x7fffu + ((u >> 16) & 1u)) >> 16);
}
__device__ __forceinline__ float lo16(u32 u) { return __uint_as_float(u << 16); }
__device__ __forceinline__ float hi16(u32 u) { return __uint_as_float(u & 0xffff0000u); }
__device__ __forceinline__ u32 pk(float a, float b) {
    return (u32)f2bf(a) | ((u32)f2bf(b) << 16);
}

template <bool IS32>
__device__ __forceinline__ float ldf(const void* p, int i) {
    return IS32 ? ((const float*)p)[i] : bf2f(((const u16*)p)[i]);
}
template <bool IS32>
__device__ __forceinline__ u16 ldbf(const void* p, int i) {
    return IS32 ? f2bf(((const float*)p)[i]) : ((const u16*)p)[i];
}

__device__ __forceinline__ float lipswish(float x) {
    return 0.909f * x / (1.0f + __expf(-x));
}
__device__ __forceinline__ float tanh_fast(float x) {
    float e = __expf(2.0f * fabsf(x));   // may be +inf -> t = 1
    float t = 1.0f - 2.0f / (e + 1.0f);
    return copysignf(t, x);
}

struct __align__(16) SMem {
    u32 vW0p[WID][33];    // pairs of bf16 along K (65 -> 33 pairs, last hi=0)
    u32 cW0p[WID][33];
    u32 vW1p[WID][65];    // 64 pairs + 1 pad column
    u32 cW1p[WID][65];
    u32 vW2p[HDIM][65];
    float vb0[WID], vb1[WID], vb2[HDIM], vsc[HDIM];
    float cb0[WID], cb1[WID];
    float cb2[HN];
    float csc[HN];
    float roW[8][HDIM];
    float rob[8];
    float tsb[1028];
    float x[BB][68];      // [t, y(64), 0pad]; stride 68 keeps rows 16B-aligned
    float h1[2][BB][WID];
    float h2[2][BB][WID];
    float yb[BB][HDIM];
    float fdt[BB][HDIM];
    float g0b[BB][HDIM];
    float gs[BB][HDIM];
    float dwb[BB][NZ];
};

__device__ __forceinline__ float dot64p(const u32* __restrict__ Wp, const float2* __restrict__ xp) {
    float a0 = 0.f, a1 = 0.f, a2 = 0.f, a3 = 0.f;
    #pragma unroll
    for (int kk = 0; kk < 64; kk += 4) {
        u32 w0 = Wp[kk], w1 = Wp[kk+1], w2 = Wp[kk+2], w3 = Wp[kk+3];
        float2 x0 = xp[kk], x1 = xp[kk+1], x2 = xp[kk+2], x3 = xp[kk+3];
        a0 = fmaf(lo16(w0), x0.x, fmaf(hi16(w0), x0.y, a0));
        a1 = fmaf(lo16(w1), x1.x, fmaf(hi16(w1), x1.y, a1));
        a2 = fmaf(lo16(w2), x2.x, fmaf(hi16(w2), x2.y, a2));
        a3 = fmaf(lo16(w3), x3.x, fmaf(hi16(w3), x3.y, a3));
    }
    return (a0 + a1) + (a2 + a3);
}

__device__ __forceinline__ float dot33p(const u32* __restrict__ Wp, const float2* __restrict__ xp) {
    float a0 = 0.f, a1 = 0.f, a2 = 0.f, a3 = 0.f;
    #pragma unroll
    for (int kk = 0; kk < 32; kk += 4) {
        u32 w0 = Wp[kk], w1 = Wp[kk+1], w2 = Wp[kk+2], w3 = Wp[kk+3];
        float2 x0 = xp[kk], x1 = xp[kk+1], x2 = xp[kk+2], x3 = xp[kk+3];
        a0 = fmaf(lo16(w0), x0.x, fmaf(hi16(w0), x0.y, a0));
        a1 = fmaf(lo16(w1), x1.x, fmaf(hi16(w1), x1.y, a1));
        a2 = fmaf(lo16(w2), x2.x, fmaf(hi16(w2), x2.y, a2));
        a3 = fmaf(lo16(w3), x3.x, fmaf(hi16(w3), x3.y, a3));
    }
    u32 wl = Wp[32]; float2 xv = xp[32];
    a0 = fmaf(lo16(wl), xv.x, fmaf(hi16(wl), xv.y, a0));
    return (a0 + a1) + (a2 + a3);
}

// function, not macro (Round 1: macro param 'w' collided with member '.w')
__device__ __forceinline__ void bigrow(float& acc, const uint4& wv, const float4& pv, const float4& qv) {
    acc = fmaf(lo16(wv.x), pv.x, acc);
    acc = fmaf(hi16(wv.x), pv.y, acc);
    acc = fmaf(lo16(wv.y), pv.z, acc);
    acc = fmaf(hi16(wv.y), pv.w, acc);
    acc = fmaf(lo16(wv.z), qv.x, acc);
    acc = fmaf(hi16(wv.z), qv.y, acc);
    acc = fmaf(lo16(wv.w), qv.z, acc);
    acc = fmaf(hi16(wv.w), qv.w, acc);
}

__device__ __forceinline__ void big_layer(SMem& sm, const uint4 (&wr)[32], int tid) {
    const int r0 = 2 * tid;
    float a00 = sm.cb2[r0], a01 = sm.cb2[r0 + 1];
    float a10 = a00, a11 = a01;
    const float4* hA = (const float4*)sm.h2[1][0];
    const float4* hB = (const float4*)sm.h2[1][1];
    #pragma unroll
    for (int i = 0; i < 16; ++i) {
        uint4 wa = wr[i];
        uint4 wb = wr[16 + i];
        float4 p0 = hA[2*i], q0 = hA[2*i + 1];
        float4 p1 = hB[2*i], q1 = hB[2*i + 1];
        bigrow(a00, wa, p0, q0);
        bigrow(a01, wb, p0, q0);
        bigrow(a10, wa, p1, q1);
        bigrow(a11, wb, p1, q1);
    }
    const float c0 = sm.csc[r0], c1 = sm.csc[r0 + 1];
    const int n0 = r0 & 15;
    float v0 = c0 * tanh_fast(a00) * sm.dwb[0][n0] + c1 * tanh_fast(a01) * sm.dwb[0][n0 + 1];
    float v1 = c0 * tanh_fast(a10) * sm.dwb[1][n0] + c1 * tanh_fast(a11) * sm.dwb[1][n0 + 1];
    #pragma unroll
    for (int m = 1; m < 8; m <<= 1) {
        v0 += __shfl_xor(v0, m);
        v1 += __shfl_xor(v1, m);
    }
    if ((tid & 7) == 0) {
        sm.gs[0][tid >> 3] = v0;
        sm.gs[1][tid >> 3] = v1;
    }
}

template <bool IS32>
__device__ __forceinline__ void stage_dw(SMem& sm, const uint4& d, int q, float sdt) {
    if (IS32) {
        const float* pf = (const float*)&d;
        int f = q * 4;
        #pragma unroll
        for (int k = 0; k < 4; ++k)
            sm.dwb[(f + k) >> 4][(f + k) & 15] = pf[k] * sdt;
    } else {
        int f = q * 8;
        u32 u0 = d.x, u1 = d.y, u2 = d.z, u3 = d.w;
        sm.dwb[(f    ) >> 4][(f    ) & 15] = lo16(u0) * sdt;
        sm.dwb[(f + 1) >> 4][(f + 1) & 15] = hi16(u0) * sdt;
        sm.dwb[(f + 2) >> 4][(f + 2) & 15] = lo16(u1) * sdt;
        sm.dwb[(f + 3) >> 4][(f + 3) & 15] = hi16(u1) * sdt;
        sm.dwb[(f + 4) >> 4][(f + 4) & 15] = lo16(u2) * sdt;
        sm.dwb[(f + 5) >> 4][(f + 5) & 15] = hi16(u2) * sdt;
        sm.dwb[(f + 6) >> 4][(f + 6) & 15] = lo16(u3) * sdt;
        sm.dwb[(f + 7) >> 4][(f + 7) & 15] = hi16(u3) * sdt;
    }
}

template <bool IS32>
__device__ __forceinline__ void write_out(void* out, size_t idx, const float* v8) {
    if (IS32) {
        float4 o0, o1;
        o0.x = v8[0]; o0.y = v8[1]; o0.z = v8[2]; o0.w = v8[3];
        o1.x = v8[4]; o1.y = v8[5]; o1.z = v8[6]; o1.w = v8[7];
        ((float4*)out)[idx * 2]     = o0;
        ((float4*)out)[idx * 2 + 1] = o1;
    } else {
        uint4 o;
        o.x = pk(v8[0], v8[1]);
        o.y = pk(v8[2], v8[3]);
        o.z = pk(v8[4], v8[5]);
        o.w = pk(v8[6], v8[7]);
        ((uint4*)out)[idx] = o;
    }
}

template <bool IS32>
__device__ __forceinline__ void
sde_run(SMem& sm,
        const void* ts,  const void* z0,  const void* dW,
        const void* iW0, const void* ib0, const void* iW1, const void* ib1,
        const void* iW2, const void* ib2,
        const void* vW0, const void* vb0, const void* vW1, const void* vb1,
        const void* vW2, const void* vb2, const void* vsc,
        const void* cW0, const void* cb0, const void* cW1, const void* cb1,
        const void* cW2, const void* cb2, const void* csc,
        const void* roW, const void* rob, void* out,
        int tid, int bid)
{
    // ---- cW2 rows 2*tid, 2*tid+1 -> registers (bf16-packed), straight-line ----
    uint4 wr[32];
    if (!IS32) {
        const uint4* p0 = (const uint4*)((const u16*)cW2 + (size_t)(2 * tid)     * WID);
        const uint4* p1 = (const uint4*)((const u16*)cW2 + (size_t)(2 * tid + 1) * WID);
        #pragma unroll
        for (int i = 0; i < 16; ++i) wr[i] = p0[i];
        #pragma unroll
        for (int i = 0; i < 16; ++i) wr[16 + i] = p1[i];
    } else {
        const float4* f0 = (const float4*)((const float*)cW2 + (size_t)(2 * tid)     * WID);
        const float4* f1 = (const float4*)((const float*)cW2 + (size_t)(2 * tid + 1) * WID);
        #pragma unroll
        for (int i = 0; i < 16; ++i) {
            float4 a = f0[2*i], b = f0[2*i+1];
            uint4 w; w.x = pk(a.x, a.y); w.y = pk(a.z, a.w); w.z = pk(b.x, b.y); w.w = pk(b.z, b.w);
            wr[i] = w;
        }
        #pragma unroll
        for (int i = 0; i < 16; ++i) {
            float4 a = f1[2*i], b = f1[2*i+1];
            uint4 w; w.x = pk(a.x, a.y); w.y = pk(a.z, a.w); w.z = pk(b.x, b.y); w.w = pk(b.z, b.w);
            wr[16 + i] = w;
        }
    }

    // ---- stage weights into LDS as packed bf16 pairs ----
    for (int idx = tid; idx < WID * 33; idx += NTHREADS) {
        int j = idx / 33, kk = idx - j * 33;
        int k0 = 2 * kk;
        u32 lo, hi;
        lo = ldbf<IS32>(vW0, j * IND + k0);
        hi = (k0 + 1 < IND) ? (u32)ldbf<IS32>(vW0, j * IND + k0 + 1) : 0u;
        sm.vW0p[j][kk] = lo | (hi << 16);
        lo = ldbf<IS32>(cW0, j * IND + k0);
        hi = (k0 + 1 < IND) ? (u32)ldbf<IS32>(cW0, j * IND + k0 + 1) : 0u;
        sm.cW0p[j][kk] = lo | (hi << 16);
    }
    for (int idx = tid; idx < WID * 65; idx += NTHREADS) {
        int j = idx / 65, kk = idx - j * 65;
        u32 v = 0, c = 0;
        if (kk < 64) {
            int k0 = 2 * kk;
            v = (u32)ldbf<IS32>(vW1, j * WID + k0) | ((u32)ldbf<IS32>(vW1, j * WID + k0 + 1) << 16);
            c = (u32)ldbf<IS32>(cW1, j * WID + k0) | ((u32)ldbf<IS32>(cW1, j * WID + k0 + 1) << 16);
        }
        sm.vW1p[j][kk] = v;
        sm.cW1p[j][kk] = c;
    }
    for (int idx = tid; idx < HDIM * 65; idx += NTHREADS) {
        int j = idx / 65, kk = idx - j * 65;
        u32 v = 0;
        if (kk < 64) {
            int k0 = 2 * kk;
            v = (u32)ldbf<IS32>(vW2, j * WID + k0) | ((u32)ldbf<IS32>(vW2, j * WID + k0 + 1) << 16);
        }
        sm.vW2p[j][kk] = v;
    }
    if (tid < WID) {
        sm.vb0[tid] = ldf<IS32>(vb0, tid); sm.vb1[tid] = ldf<IS32>(vb1, tid);
        sm.cb0[tid] = ldf<IS32>(cb0, tid); sm.cb1[tid] = ldf<IS32>(cb1, tid);
        if (tid < HDIM) { sm.vb2[tid] = ldf<IS32>(vb2, tid); sm.vsc[tid] = ldf<IS32>(vsc, tid); }
        if (tid < 8) sm.rob[tid] = ldf<IS32>(rob, tid);
    }
    for (int i = tid; i < HN; i += NTHREADS) {
        sm.cb2[i] = ldf<IS32>(cb2, i);
        sm.csc[i] = ldf<IS32>(csc, i);
    }
    { int d = tid >> 6, i2 = tid & 63; sm.roW[d][i2] = ldf<IS32>(roW, tid); }
    for (int i = tid; i < TPTS; i += NTHREADS) sm.tsb[i] = ldf<IS32>(ts, i);

    // prefetch dW for step 0
    uint4 dwpref;
    if (tid >= 128 && tid < 136) {
        int q = tid - 128;
        if (IS32)       dwpref = ((const uint4*)dW)[(size_t)bid * 8 + q];       // 8 x float4
        else if (q < 4) dwpref = ((const uint4*)dW)[(size_t)bid * 4 + q];       // 4 x bf16x8
    }

    __syncthreads();

    const float dt  = sm.tsb[1] - sm.tsb[0];
    const float sdt = sqrtf(dt);

    if (tid >= 128 && tid < 136) {
        int q = tid - 128;
        if (IS32 || q < 4) stage_dw<IS32>(sm, dwpref, q, sdt);
    }

    // ---- initial MLP (relu, relu, identity): z0(8) -> 128 -> 128 -> y0(64) ----
    if (tid < 256) {   // I1
        int b = tid >> 7, j = tid & 127;
        float acc = ldf<IS32>(ib0, j);
        #pragma unroll
        for (int k = 0; k < 8; ++k)
            acc = fmaf(ldf<IS32>(iW0, j * 8 + k), ldf<IS32>(z0, (bid * BB + b) * 8 + k), acc);
        sm.h1[0][b][j] = fmaxf(acc, 0.0f);
    }
    __syncthreads();
    if (tid < 256) {   // I2
        int b = tid >> 7, j = tid & 127;
        float acc = ldf<IS32>(ib1, j);
        for (int k = 0; k < WID; ++k)
            acc = fmaf(ldf<IS32>(iW1, j * WID + k), sm.h1[0][b][k], acc);
        sm.h2[0][b][j] = fmaxf(acc, 0.0f);
    }
    __syncthreads();
    if (tid < 128) {   // I3: y0, x init, t=0 readout
        int b = tid >> 6, i = tid & 63;
        float y0 = ldf<IS32>(ib2, i);
        for (int k = 0; k < WID; ++k)
            y0 = fmaf(ldf<IS32>(iW2, i * WID + k), sm.h2[0][b][k], y0);
        sm.yb[b][i] = y0;
        sm.x[b][1 + i] = y0;
        if (i == 0) {
            sm.x[b][0] = sm.tsb[0];
            sm.x[b][65] = 0.0f; sm.x[b][66] = 0.0f; sm.x[b][67] = 0.0f;
        }
        float acc[8];
        #pragma unroll
        for (int d = 0; d < 8; ++d) acc[d] = sm.roW[d][i] * y0;
        #pragma unroll
        for (int m = 1; m < 64; m <<= 1) {
            #pragma unroll
            for (int d = 0; d < 8; ++d) acc[d] += __shfl_xor(acc[d], m);
        }
        if (i == 0) {
            float v8[8];
            #pragma unroll
            for (int d = 0; d < 8; ++d) v8[d] = acc[d] + sm.rob[d];
            write_out<IS32>(out, (size_t)(bid * BB + b) * TPTS, v8);
        }
    }
    __syncthreads();

    // ---- main scan: 1024 Euler-Heun steps ----
    for (int s = 0; s < STEPS; ++s) {
        if (s + 1 < STEPS && tid >= 128 && tid < 136) {
            int q = tid - 128;
            if (IS32)       dwpref = ((const uint4*)dW)[(size_t)(s + 1) * 2048 + bid * 8 + q];
            else if (q < 4) dwpref = ((const uint4*)dW)[(size_t)(s + 1) * 1024 + bid * 4 + q];
        }
        // P2: fused L0 for drift(v=0) and diffusion(c=1), input x=[t,y]
        {
            const int mlp = tid >> 8, b = (tid >> 7) & 1, j = tid & 127;
            const u32* Wp = mlp ? sm.cW0p[j] : sm.vW0p[j];
            const float bias = mlp ? sm.cb0[j] : sm.vb0[j];
            float acc = bias + dot33p(Wp, (const float2*)sm.x[b]);
            sm.h1[mlp][b][j] = lipswish(acc);
        }
        __syncthreads();
        // P3: fused L1
        {
            const int mlp = tid >> 8, b = (tid >> 7) & 1, j = tid & 127;
            const u32* Wp = mlp ? sm.cW1p[j] : sm.vW1p[j];
            const float bias = mlp ? sm.cb1[j] : sm.vb1[j];
            float acc = bias + dot64p(Wp, (const float2*)sm.h1[mlp][b]);
            sm.h2[mlp][b][j] = lipswish(acc);
        }
        __syncthreads();
        // P4: diffusion big layer eval 1 -> gs = g0
        big_layer(sm, wr, tid);
        __syncthreads();
        // P5: x' = y + g0 (waves 0-1) | drift L2 -> fdt (waves 2-3)
        if (tid < 128) {
            int b = tid >> 6, i = tid & 63;
            float g0 = sm.gs[b][i];
            sm.g0b[b][i] = g0;
            sm.x[b][1 + i] = sm.yb[b][i] + g0;
        } else if (tid < 256) {
            int q = tid - 128, b = q >> 6, j = q & 63;
            float acc = sm.vb2[j] + dot64p(sm.vW2p[j], (const float2*)sm.h2[0][b]);
            sm.fdt[b][j] = sm.vsc[j] * tanh_fast(acc) * dt;
        }
        __syncthreads();
        // P6: diffusion L0 on x'
        if (tid < 256) {
            int b = tid >> 7, j = tid & 127;
            float acc = sm.cb0[j] + dot33p(sm.cW0p[j], (const float2*)sm.x[b]);
            sm.h1[1][b][j] = lipswish(acc);
        }
        __syncthreads();
        // P7: diffusion L1
        if (tid < 256) {
            int b = tid >> 7, j = tid & 127;
            float acc = sm.cb1[j] + dot64p(sm.cW1p[j], (const float2*)sm.h1[1][b]);
            sm.h2[1][b][j] = lipswish(acc);
        }
        __syncthreads();
        // P8: diffusion big layer eval 2 -> gs = g1
        big_layer(sm, wr, tid);
        __syncthreads();
        // P9: y1 = y + f0*dt + 0.5*(g0+g1); readout; stage next x and dw
        if (tid < 128) {
            int b = tid >> 6, i = tid & 63;
            float y1 = sm.yb[b][i] + sm.fdt[b][i] + 0.5f * (sm.g0b[b][i] + sm.gs[b][i]);
            sm.yb[b][i] = y1;
            sm.x[b][1 + i] = y1;
            if (i == 0) sm.x[b][0] = sm.tsb[s + 1];
            float acc[8];
            #pragma unroll
            for (int d = 0; d < 8; ++d) acc[d] = sm.roW[d][i] * y1;
            #pragma unroll
            for (int m = 1; m < 64; m <<= 1) {
                #pragma unroll
                for (int d = 0; d < 8; ++d) acc[d] += __shfl_xor(acc[d], m);
            }
            if (i == 0) {
                float v8[8];
                #pragma unroll
                for (int d = 0; d < 8; ++d) v8[d] = acc[d] + sm.rob[d];
                write_out<IS32>(out, (size_t)(bid * BB + b) * TPTS + (s + 1), v8);
            }
        } else if (tid >= 128 && tid < 136 && s + 1 < STEPS) {
            int q = tid - 128;
            if (IS32 || q < 4) stage_dw<IS32>(sm, dwpref, q, sdt);
        }
        __syncthreads();
    }
}

// amdgpu_waves_per_eu(2,2): R3/R4 showed __launch_bounds__ min-waves alone leaves
// the allocator targeting 4 waves/EU -> 128-VGPR cap -> wr[] spilled to scratch
// (24.7 GB FETCH/dispatch). Capping the occupancy target MAX at 2 waves/EU gives
// a 256-VGPR budget; LDS (137 KB) pins us to 1 block/CU = 2 waves/EU anyway.
__global__ void
__attribute__((amdgpu_flat_work_group_size(NTHREADS, NTHREADS), amdgpu_waves_per_eu(2, 2)))
sde_kernel(const void* __restrict__ ts,  const void* __restrict__ z0,  const void* __restrict__ dW,
           const void* __restrict__ iW0, const void* __restrict__ ib0, const void* __restrict__ iW1,
           const void* __restrict__ ib1, const void* __restrict__ iW2, const void* __restrict__ ib2,
           const void* __restrict__ vW0, const void* __restrict__ vb0, const void* __restrict__ vW1,
           const void* __restrict__ vb1, const void* __restrict__ vW2, const void* __restrict__ vb2,
           const void* __restrict__ vsc, const void* __restrict__ cW0, const void* __restrict__ cb0,
           const void* __restrict__ cW1, const void* __restrict__ cb1, const void* __restrict__ cW2,
           const void* __restrict__ cb2, const void* __restrict__ csc, const void* __restrict__ roW,
           const void* __restrict__ rob, void* __restrict__ out)
{
    __shared__ SMem sm;
    const int tid = threadIdx.x;
    const int bid = blockIdx.x;

    // dtype detection: u16 word #1 of ts. bf16: bf16(1/1024)=0x3A80 != 0.
    // fp32: high half of 0.0f == 0.
    const bool is32 = (((const u16*)ts)[1] == 0);

    if (is32) {
        sde_run<true>(sm, ts, z0, dW, iW0, ib0, iW1, ib1, iW2, ib2,
                      vW0, vb0, vW1, vb1, vW2, vb2, vsc,
                      cW0, cb0, cW1, cb1, cW2, cb2, csc, roW, rob, out, tid, bid);
    } else {
        sde_run<false>(sm, ts, z0, dW, iW0, ib0, iW1, ib1, iW2, ib2,
                       vW0, vb0, vW1, vb1, vW2, vb2, vsc,
                       cW0, cb0, cW1, cb1, cW2, cb2, csc, roW, rob, out, tid, bid);
    }
}

extern "C" void kernel_launch(void* const* d_in, const int* in_sizes, int n_in,
                              void* d_out, int out_size, void* d_ws, size_t ws_size,
                              hipStream_t stream) {
    (void)in_sizes; (void)n_in; (void)d_ws; (void)ws_size; (void)out_size;
    hipLaunchKernelGGL(sde_kernel, dim3(NBLOCKS), dim3(NTHREADS), 0, stream,
                       d_in[0], d_in[1], d_in[2], d_in[3], d_in[4], d_in[5], d_in[6],
                       d_in[7], d_in[8], d_in[9], d_in[10], d_in[11], d_in[12], d_in[13],
                       d_in[14], d_in[15], d_in[16], d_in[17], d_in[18], d_in[19], d_in[20],
                       d_in[21], d_in[22], d_in[23], d_in[24], d_out);
}

// Round 6
// 16819.933 us; speedup vs baseline: 1.5767x; 1.5666x over previous
//
#include <hip/hip_runtime.h>

typedef unsigned short u16;
typedef unsigned int   u32;
typedef __attribute__((ext_vector_type(4))) unsigned int au4;

#define NTHREADS 512
#define NBLOCKS  256
#define BB       2
#define STEPS    1024
#define TPTS     1025
#define HDIM     64
#define NZ       16
#define WID      128
#define IND      65
#define HN       1024

__device__ __forceinline__ float bf2f(u16 v) { return __uint_as_float(((u32)v) << 16); }
__device__ __forceinline__ u16 f2bf(float f) {
    u32 u = __float_as_uint(f);
    return (u16)((u + 0x7fffu + ((u >> 16) & 1u)) >> 16);
}
__device__ __forceinline__ float lo16(u32 u) { return __uint_as_float(u << 16); }
__device__ __forceinline__ float hi16(u32 u) { return __uint_as_float(u & 0xffff0000u); }
__device__ __forceinline__ u32 pk(float a, float b) {
    return (u32)f2bf(a) | ((u32)f2bf(b) << 16);
}

// ---- AGPR pinning (R5 post-mortem): the scheduler sinks loop-invariant global
// loads of cW2 back into the step loop if the values live in VGPR pressure.
// Home them in AGPRs via empty-asm class laundering; volatile use-side reads
// stop LICM from hoisting them back into VGPRs for the whole loop.
__device__ __forceinline__ au4 apin(uint4 v) {
    au4 t; t.x = v.x; t.y = v.y; t.z = v.z; t.w = v.w;
    au4 r;
    asm volatile("" : "=a"(r) : "0"(t));
    return r;
}
__device__ __forceinline__ uint4 aget(au4 a) {
    au4 t;
    asm volatile("" : "=v"(t) : "0"(a));
    uint4 r; r.x = t.x; r.y = t.y; r.z = t.z; r.w = t.w;
    return r;
}

template <bool IS32>
__device__ __forceinline__ float ldf(const void* p, int i) {
    return IS32 ? ((const float*)p)[i] : bf2f(((const u16*)p)[i]);
}
template <bool IS32>
__device__ __forceinline__ u16 ldbf(const void* p, int i) {
    return IS32 ? f2bf(((const float*)p)[i]) : ((const u16*)p)[i];
}

__device__ __forceinline__ float lipswish(float x) {
    return 0.909f * x / (1.0f + __expf(-x));
}
__device__ __forceinline__ float tanh_fast(float x) {
    float e = __expf(2.0f * fabsf(x));   // may be +inf -> t = 1
    float t = 1.0f - 2.0f / (e + 1.0f);
    return copysignf(t, x);
}

struct __align__(16) SMem {
    u32 vW0p[WID][33];    // pairs of bf16 along K (65 -> 33 pairs, last hi=0)
    u32 cW0p[WID][33];
    u32 vW1p[WID][65];    // 64 pairs + 1 pad column
    u32 cW1p[WID][65];
    u32 vW2p[HDIM][65];
    float vb0[WID], vb1[WID], vb2[HDIM], vsc[HDIM];
    float cb0[WID], cb1[WID];
    float cb2[HN];
    float csc[HN];
    float roW[8][HDIM];
    float rob[8];
    float tsb[1028];
    float x[BB][68];      // [t, y(64), 0pad]; stride 68 keeps rows 16B-aligned
    float h1[2][BB][WID];
    float h2[2][BB][WID];
    float yb[BB][HDIM];
    float fdt[BB][HDIM];
    float g0b[BB][HDIM];
    float gs[BB][HDIM];
    float dwb[BB][NZ];
};

__device__ __forceinline__ float dot64p(const u32* __restrict__ Wp, const float2* __restrict__ xp) {
    float a0 = 0.f, a1 = 0.f, a2 = 0.f, a3 = 0.f;
    #pragma unroll
    for (int kk = 0; kk < 64; kk += 4) {
        u32 w0 = Wp[kk], w1 = Wp[kk+1], w2 = Wp[kk+2], w3 = Wp[kk+3];
        float2 x0 = xp[kk], x1 = xp[kk+1], x2 = xp[kk+2], x3 = xp[kk+3];
        a0 = fmaf(lo16(w0), x0.x, fmaf(hi16(w0), x0.y, a0));
        a1 = fmaf(lo16(w1), x1.x, fmaf(hi16(w1), x1.y, a1));
        a2 = fmaf(lo16(w2), x2.x, fmaf(hi16(w2), x2.y, a2));
        a3 = fmaf(lo16(w3), x3.x, fmaf(hi16(w3), x3.y, a3));
    }
    return (a0 + a1) + (a2 + a3);
}

__device__ __forceinline__ float dot33p(const u32* __restrict__ Wp, const float2* __restrict__ xp) {
    float a0 = 0.f, a1 = 0.f, a2 = 0.f, a3 = 0.f;
    #pragma unroll
    for (int kk = 0; kk < 32; kk += 4) {
        u32 w0 = Wp[kk], w1 = Wp[kk+1], w2 = Wp[kk+2], w3 = Wp[kk+3];
        float2 x0 = xp[kk], x1 = xp[kk+1], x2 = xp[kk+2], x3 = xp[kk+3];
        a0 = fmaf(lo16(w0), x0.x, fmaf(hi16(w0), x0.y, a0));
        a1 = fmaf(lo16(w1), x1.x, fmaf(hi16(w1), x1.y, a1));
        a2 = fmaf(lo16(w2), x2.x, fmaf(hi16(w2), x2.y, a2));
        a3 = fmaf(lo16(w3), x3.x, fmaf(hi16(w3), x3.y, a3));
    }
    u32 wl = Wp[32]; float2 xv = xp[32];
    a0 = fmaf(lo16(wl), xv.x, fmaf(hi16(wl), xv.y, a0));
    return (a0 + a1) + (a2 + a3);
}

// function, not macro (Round 1: macro param 'w' collided with member '.w')
__device__ __forceinline__ void bigrow(float& acc, const uint4& wv, const float4& pv, const float4& qv) {
    acc = fmaf(lo16(wv.x), pv.x, acc);
    acc = fmaf(hi16(wv.x), pv.y, acc);
    acc = fmaf(lo16(wv.y), pv.z, acc);
    acc = fmaf(hi16(wv.y), pv.w, acc);
    acc = fmaf(lo16(wv.z), qv.x, acc);
    acc = fmaf(hi16(wv.z), qv.y, acc);
    acc = fmaf(lo16(wv.w), qv.z, acc);
    acc = fmaf(hi16(wv.w), qv.w, acc);
}

__device__ __forceinline__ void big_layer(SMem& sm, const au4 (&ag)[32], int tid) {
    const int r0 = 2 * tid;
    float a00 = sm.cb2[r0], a01 = sm.cb2[r0 + 1];
    float a10 = a00, a11 = a01;
    const float4* hA = (const float4*)sm.h2[1][0];
    const float4* hB = (const float4*)sm.h2[1][1];
    #pragma unroll
    for (int i = 0; i < 16; ++i) {
        uint4 wa = aget(ag[i]);        // row r0, k = 8i..8i+7 (AGPR -> VGPR)
        uint4 wb = aget(ag[16 + i]);   // row r0+1
        float4 p0 = hA[2*i], q0 = hA[2*i + 1];
        float4 p1 = hB[2*i], q1 = hB[2*i + 1];
        bigrow(a00, wa, p0, q0);
        bigrow(a01, wb, p0, q0);
        bigrow(a10, wa, p1, q1);
        bigrow(a11, wb, p1, q1);
    }
    const float c0 = sm.csc[r0], c1 = sm.csc[r0 + 1];
    const int n0 = r0 & 15;
    float v0 = c0 * tanh_fast(a00) * sm.dwb[0][n0] + c1 * tanh_fast(a01) * sm.dwb[0][n0 + 1];
    float v1 = c0 * tanh_fast(a10) * sm.dwb[1][n0] + c1 * tanh_fast(a11) * sm.dwb[1][n0 + 1];
    #pragma unroll
    for (int m = 1; m < 8; m <<= 1) {
        v0 += __shfl_xor(v0, m);
        v1 += __shfl_xor(v1, m);
    }
    if ((tid & 7) == 0) {
        sm.gs[0][tid >> 3] = v0;
        sm.gs[1][tid >> 3] = v1;
    }
}

template <bool IS32>
__device__ __forceinline__ void stage_dw(SMem& sm, const uint4& d, int q, float sdt) {
    if (IS32) {
        const float* pf = (const float*)&d;
        int f = q * 4;
        #pragma unroll
        for (int k = 0; k < 4; ++k)
            sm.dwb[(f + k) >> 4][(f + k) & 15] = pf[k] * sdt;
    } else {
        int f = q * 8;
        u32 u0 = d.x, u1 = d.y, u2 = d.z, u3 = d.w;
        sm.dwb[(f    ) >> 4][(f    ) & 15] = lo16(u0) * sdt;
        sm.dwb[(f + 1) >> 4][(f + 1) & 15] = hi16(u0) * sdt;
        sm.dwb[(f + 2) >> 4][(f + 2) & 15] = lo16(u1) * sdt;
        sm.dwb[(f + 3) >> 4][(f + 3) & 15] = hi16(u1) * sdt;
        sm.dwb[(f + 4) >> 4][(f + 4) & 15] = lo16(u2) * sdt;
        sm.dwb[(f + 5) >> 4][(f + 5) & 15] = hi16(u2) * sdt;
        sm.dwb[(f + 6) >> 4][(f + 6) & 15] = lo16(u3) * sdt;
        sm.dwb[(f + 7) >> 4][(f + 7) & 15] = hi16(u3) * sdt;
    }
}

template <bool IS32>
__device__ __forceinline__ void write_out(void* out, size_t idx, const float* v8) {
    if (IS32) {
        float4 o0, o1;
        o0.x = v8[0]; o0.y = v8[1]; o0.z = v8[2]; o0.w = v8[3];
        o1.x = v8[4]; o1.y = v8[5]; o1.z = v8[6]; o1.w = v8[7];
        ((float4*)out)[idx * 2]     = o0;
        ((float4*)out)[idx * 2 + 1] = o1;
    } else {
        uint4 o;
        o.x = pk(v8[0], v8[1]);
        o.y = pk(v8[2], v8[3]);
        o.z = pk(v8[4], v8[5]);
        o.w = pk(v8[6], v8[7]);
        ((uint4*)out)[idx] = o;
    }
}

template <bool IS32>
__device__ __forceinline__ void
sde_run(SMem& sm,
        const void* ts,  const void* z0,  const void* dW,
        const void* iW0, const void* ib0, const void* iW1, const void* ib1,
        const void* iW2, const void* ib2,
        const void* vW0, const void* vb0, const void* vW1, const void* vb1,
        const void* vW2, const void* vb2, const void* vsc,
        const void* cW0, const void* cb0, const void* cW1, const void* cb1,
        const void* cW2, const void* cb2, const void* csc,
        const void* roW, const void* rob, void* out,
        int tid, int bid)
{
    // ---- cW2 rows 2*tid, 2*tid+1 -> AGPRs (bf16-packed) ----
    au4 ag[32];
    if (!IS32) {
        const uint4* p0 = (const uint4*)((const u16*)cW2 + (size_t)(2 * tid)     * WID);
        const uint4* p1 = (const uint4*)((const u16*)cW2 + (size_t)(2 * tid + 1) * WID);
        #pragma unroll
        for (int i = 0; i < 16; ++i) ag[i] = apin(p0[i]);
        #pragma unroll
        for (int i = 0; i < 16; ++i) ag[16 + i] = apin(p1[i]);
    } else {
        const float4* f0 = (const float4*)((const float*)cW2 + (size_t)(2 * tid)     * WID);
        const float4* f1 = (const float4*)((const float*)cW2 + (size_t)(2 * tid + 1) * WID);
        #pragma unroll
        for (int i = 0; i < 16; ++i) {
            float4 a = f0[2*i], b = f0[2*i+1];
            uint4 w; w.x = pk(a.x, a.y); w.y = pk(a.z, a.w); w.z = pk(b.x, b.y); w.w = pk(b.z, b.w);
            ag[i] = apin(w);
        }
        #pragma unroll
        for (int i = 0; i < 16; ++i) {
            float4 a = f1[2*i], b = f1[2*i+1];
            uint4 w; w.x = pk(a.x, a.y); w.y = pk(a.z, a.w); w.z = pk(b.x, b.y); w.w = pk(b.z, b.w);
            ag[16 + i] = apin(w);
        }
    }

    // ---- stage weights into LDS as packed bf16 pairs ----
    for (int idx = tid; idx < WID * 33; idx += NTHREADS) {
        int j = idx / 33, kk = idx - j * 33;
        int k0 = 2 * kk;
        u32 lo, hi;
        lo = ldbf<IS32>(vW0, j * IND + k0);
        hi = (k0 + 1 < IND) ? (u32)ldbf<IS32>(vW0, j * IND + k0 + 1) : 0u;
        sm.vW0p[j][kk] = lo | (hi << 16);
        lo = ldbf<IS32>(cW0, j * IND + k0);
        hi = (k0 + 1 < IND) ? (u32)ldbf<IS32>(cW0, j * IND + k0 + 1) : 0u;
        sm.cW0p[j][kk] = lo | (hi << 16);
    }
    for (int idx = tid; idx < WID * 65; idx += NTHREADS) {
        int j = idx / 65, kk = idx - j * 65;
        u32 v = 0, c = 0;
        if (kk < 64) {
            int k0 = 2 * kk;
            v = (u32)ldbf<IS32>(vW1, j * WID + k0) | ((u32)ldbf<IS32>(vW1, j * WID + k0 + 1) << 16);
            c = (u32)ldbf<IS32>(cW1, j * WID + k0) | ((u32)ldbf<IS32>(cW1, j * WID + k0 + 1) << 16);
        }
        sm.vW1p[j][kk] = v;
        sm.cW1p[j][kk] = c;
    }
    for (int idx = tid; idx < HDIM * 65; idx += NTHREADS) {
        int j = idx / 65, kk = idx - j * 65;
        u32 v = 0;
        if (kk < 64) {
            int k0 = 2 * kk;
            v = (u32)ldbf<IS32>(vW2, j * WID + k0) | ((u32)ldbf<IS32>(vW2, j * WID + k0 + 1) << 16);
        }
        sm.vW2p[j][kk] = v;
    }
    if (tid < WID) {
        sm.vb0[tid] = ldf<IS32>(vb0, tid); sm.vb1[tid] = ldf<IS32>(vb1, tid);
        sm.cb0[tid] = ldf<IS32>(cb0, tid); sm.cb1[tid] = ldf<IS32>(cb1, tid);
        if (tid < HDIM) { sm.vb2[tid] = ldf<IS32>(vb2, tid); sm.vsc[tid] = ldf<IS32>(vsc, tid); }
        if (tid < 8) sm.rob[tid] = ldf<IS32>(rob, tid);
    }
    for (int i = tid; i < HN; i += NTHREADS) {
        sm.cb2[i] = ldf<IS32>(cb2, i);
        sm.csc[i] = ldf<IS32>(csc, i);
    }
    { int d = tid >> 6, i2 = tid & 63; sm.roW[d][i2] = ldf<IS32>(roW, tid); }
    for (int i = tid; i < TPTS; i += NTHREADS) sm.tsb[i] = ldf<IS32>(ts, i);

    // prefetch dW for step 0
    uint4 dwpref;
    if (tid >= 128 && tid < 136) {
        int q = tid - 128;
        if (IS32)       dwpref = ((const uint4*)dW)[(size_t)bid * 8 + q];       // 8 x float4
        else if (q < 4) dwpref = ((const uint4*)dW)[(size_t)bid * 4 + q];       // 4 x bf16x8
    }

    __syncthreads();

    const float dt  = sm.tsb[1] - sm.tsb[0];
    const float sdt = sqrtf(dt);

    if (tid >= 128 && tid < 136) {
        int q = tid - 128;
        if (IS32 || q < 4) stage_dw<IS32>(sm, dwpref, q, sdt);
    }

    // ---- initial MLP (relu, relu, identity): z0(8) -> 128 -> 128 -> y0(64) ----
    if (tid < 256) {   // I1
        int b = tid >> 7, j = tid & 127;
        float acc = ldf<IS32>(ib0, j);
        #pragma unroll
        for (int k = 0; k < 8; ++k)
            acc = fmaf(ldf<IS32>(iW0, j * 8 + k), ldf<IS32>(z0, (bid * BB + b) * 8 + k), acc);
        sm.h1[0][b][j] = fmaxf(acc, 0.0f);
    }
    __syncthreads();
    if (tid < 256) {   // I2
        int b = tid >> 7, j = tid & 127;
        float acc = ldf<IS32>(ib1, j);
        for (int k = 0; k < WID; ++k)
            acc = fmaf(ldf<IS32>(iW1, j * WID + k), sm.h1[0][b][k], acc);
        sm.h2[0][b][j] = fmaxf(acc, 0.0f);
    }
    __syncthreads();
    if (tid < 128) {   // I3: y0, x init, t=0 readout
        int b = tid >> 6, i = tid & 63;
        float y0 = ldf<IS32>(ib2, i);
        for (int k = 0; k < WID; ++k)
            y0 = fmaf(ldf<IS32>(iW2, i * WID + k), sm.h2[0][b][k], y0);
        sm.yb[b][i] = y0;
        sm.x[b][1 + i] = y0;
        if (i == 0) {
            sm.x[b][0] = sm.tsb[0];
            sm.x[b][65] = 0.0f; sm.x[b][66] = 0.0f; sm.x[b][67] = 0.0f;
        }
        float acc[8];
        #pragma unroll
        for (int d = 0; d < 8; ++d) acc[d] = sm.roW[d][i] * y0;
        #pragma unroll
        for (int m = 1; m < 64; m <<= 1) {
            #pragma unroll
            for (int d = 0; d < 8; ++d) acc[d] += __shfl_xor(acc[d], m);
        }
        if (i == 0) {
            float v8[8];
            #pragma unroll
            for (int d = 0; d < 8; ++d) v8[d] = acc[d] + sm.rob[d];
            write_out<IS32>(out, (size_t)(bid * BB + b) * TPTS, v8);
        }
    }
    __syncthreads();

    // ---- main scan: 1024 Euler-Heun steps ----
    for (int s = 0; s < STEPS; ++s) {
        if (s + 1 < STEPS && tid >= 128 && tid < 136) {
            int q = tid - 128;
            if (IS32)       dwpref = ((const uint4*)dW)[(size_t)(s + 1) * 2048 + bid * 8 + q];
            else if (q < 4) dwpref = ((const uint4*)dW)[(size_t)(s + 1) * 1024 + bid * 4 + q];
        }
        // P2: fused L0 for drift(v=0) and diffusion(c=1), input x=[t,y]
        {
            const int mlp = tid >> 8, b = (tid >> 7) & 1, j = tid & 127;
            const u32* Wp = mlp ? sm.cW0p[j] : sm.vW0p[j];
            const float bias = mlp ? sm.cb0[j] : sm.vb0[j];
            float acc = bias + dot33p(Wp, (const float2*)sm.x[b]);
            sm.h1[mlp][b][j] = lipswish(acc);
        }
        __syncthreads();
        // P3: fused L1
        {
            const int mlp = tid >> 8, b = (tid >> 7) & 1, j = tid & 127;
            const u32* Wp = mlp ? sm.cW1p[j] : sm.vW1p[j];
            const float bias = mlp ? sm.cb1[j] : sm.vb1[j];
            float acc = bias + dot64p(Wp, (const float2*)sm.h1[mlp][b]);
            sm.h2[mlp][b][j] = lipswish(acc);
        }
        __syncthreads();
        // P4: diffusion big layer eval 1 -> gs = g0
        big_layer(sm, ag, tid);
        __syncthreads();
        // P5: x' = y + g0 (waves 0-1) | drift L2 -> fdt (waves 2-3)
        if (tid < 128) {
            int b = tid >> 6, i = tid & 63;
            float g0 = sm.gs[b][i];
            sm.g0b[b][i] = g0;
            sm.x[b][1 + i] = sm.yb[b][i] + g0;
        } else if (tid < 256) {
            int q = tid - 128, b = q >> 6, j = q & 63;
            float acc = sm.vb2[j] + dot64p(sm.vW2p[j], (const float2*)sm.h2[0][b]);
            sm.fdt[b][j] = sm.vsc[j] * tanh_fast(acc) * dt;
        }
        __syncthreads();
        // P6: diffusion L0 on x'
        if (tid < 256) {
            int b = tid >> 7, j = tid & 127;
            float acc = sm.cb0[j] + dot33p(sm.cW0p[j], (const float2*)sm.x[b]);
            sm.h1[1][b][j] = lipswish(acc);
        }
        __syncthreads();
        // P7: diffusion L1
        if (tid < 256) {
            int b = tid >> 7, j = tid & 127;
            float acc = sm.cb1[j] + dot64p(sm.cW1p[j], (const float2*)sm.h1[1][b]);
            sm.h2[1][b][j] = lipswish(acc);
        }
        __syncthreads();
        // P8: diffusion big layer eval 2 -> gs = g1
        big_layer(sm, ag, tid);
        __syncthreads();
        // P9: y1 = y + f0*dt + 0.5*(g0+g1); readout; stage next x and dw
        if (tid < 128) {
            int b = tid >> 6, i = tid & 63;
            float y1 = sm.yb[b][i] + sm.fdt[b][i] + 0.5f * (sm.g0b[b][i] + sm.gs[b][i]);
            sm.yb[b][i] = y1;
            sm.x[b][1 + i] = y1;
            if (i == 0) sm.x[b][0] = sm.tsb[s + 1];
            float acc[8];
            #pragma unroll
            for (int d = 0; d < 8; ++d) acc[d] = sm.roW[d][i] * y1;
            #pragma unroll
            for (int m = 1; m < 64; m <<= 1) {
                #pragma unroll
                for (int d = 0; d < 8; ++d) acc[d] += __shfl_xor(acc[d], m);
            }
            if (i == 0) {
                float v8[8];
                #pragma unroll
                for (int d = 0; d < 8; ++d) v8[d] = acc[d] + sm.rob[d];
                write_out<IS32>(out, (size_t)(bid * BB + b) * TPTS + (s + 1), v8);
            }
        } else if (tid >= 128 && tid < 136 && s + 1 < STEPS) {
            int q = tid - 128;
            if (IS32 || q < 4) stage_dw<IS32>(sm, dwpref, q, sdt);
        }
        __syncthreads();
    }
}

__global__ void
__attribute__((amdgpu_flat_work_group_size(NTHREADS, NTHREADS), amdgpu_waves_per_eu(2, 2)))
sde_kernel(const void* __restrict__ ts,  const void* __restrict__ z0,  const void* __restrict__ dW,
           const void* __restrict__ iW0, const void* __restrict__ ib0, const void* __restrict__ iW1,
           const void* __restrict__ ib1, const void* __restrict__ iW2, const void* __restrict__ ib2,
           const void* __restrict__ vW0, const void* __restrict__ vb0, const void* __restrict__ vW1,
           const void* __restrict__ vb1, const void* __restrict__ vW2, const void* __restrict__ vb2,
           const void* __restrict__ vsc, const void* __restrict__ cW0, const void* __restrict__ cb0,
           const void* __restrict__ cW1, const void* __restrict__ cb1, const void* __restrict__ cW2,
           const void* __restrict__ cb2, const void* __restrict__ csc, const void* __restrict__ roW,
           const void* __restrict__ rob, void* __restrict__ out)
{
    __shared__ SMem sm;
    const int tid = threadIdx.x;
    const int bid = blockIdx.x;

    // dtype detection: u16 word #1 of ts. bf16: bf16(1/1024)=0x3A80 != 0.
    // fp32: high half of 0.0f == 0.
    const bool is32 = (((const u16*)ts)[1] == 0);

    if (is32) {
        sde_run<true>(sm, ts, z0, dW, iW0, ib0, iW1, ib1, iW2, ib2,
                      vW0, vb0, vW1, vb1, vW2, vb2, vsc,
                      cW0, cb0, cW1, cb1, cW2, cb2, csc, roW, rob, out, tid, bid);
    } else {
        sde_run<false>(sm, ts, z0, dW, iW0, ib0, iW1, ib1, iW2, ib2,
                       vW0, vb0, vW1, vb1, vW2, vb2, vsc,
                       cW0, cb0, cW1, cb1, cW2, cb2, csc, roW, rob, out, tid, bid);
    }
}

extern "C" void kernel_launch(void* const* d_in, const int* in_sizes, int n_in,
                              void* d_out, int out_size, void* d_ws, size_t ws_size,
                              hipStream_t stream) {
    (void)in_sizes; (void)n_in; (void)d_ws; (void)ws_size; (void)out_size;
    hipLaunchKernelGGL(sde_kernel, dim3(NBLOCKS), dim3(NTHREADS), 0, stream,
                       d_in[0], d_in[1], d_in[2], d_in[3], d_in[4], d_in[5], d_in[6],
                       d_in[7], d_in[8], d_in[9], d_in[10], d_in[11], d_in[12], d_in[13],
                       d_in[14], d_in[15], d_in[16], d_in[17], d_in[18], d_in[19], d_in[20],
                       d_in[21], d_in[22], d_in[23], d_in[24], d_out);
}

// Round 7
// 15553.369 us; speedup vs baseline: 1.7051x; 1.0814x over previous
//
#include <hip/hip_runtime.h>

typedef unsigned short u16;
typedef unsigned int   u32;
typedef __attribute__((ext_vector_type(4))) unsigned int au4;
typedef __attribute__((ext_vector_type(4))) float fx4;
typedef __attribute__((ext_vector_type(8))) __bf16 bf16x8;

#define NTHREADS 512
#define NBLOCKS  256
#define BB       2
#define STEPS    1024
#define TPTS     1025
#define HDIM     64
#define NZ       16
#define WID      128
#define IND      65
#define HN       1024

__device__ __forceinline__ float bf2f(u16 v) { return __uint_as_float(((u32)v) << 16); }
__device__ __forceinline__ u16 f2bf(float f) {
    u32 u = __float_as_uint(f);
    return (u16)((u + 0x7fffu + ((u >> 16) & 1u)) >> 16);
}
__device__ __forceinline__ float lo16(u32 u) { return __uint_as_float(u << 16); }
__device__ __forceinline__ float hi16(u32 u) { return __uint_as_float(u & 0xffff0000u); }
__device__ __forceinline__ u32 pk(float a, float b) {
    return (u32)f2bf(a) | ((u32)f2bf(b) << 16);
}

// ---- AGPR pinning (R5/R6): def-side "=a" homes cW2 fragments in AGPRs so the
// scheduler can't sink the global loads into the step loop (R6: FETCH 32 GB->23 MB).
__device__ __forceinline__ au4 apin(uint4 v) {
    au4 t; t.x = v.x; t.y = v.y; t.z = v.z; t.w = v.w;
    au4 r;
    asm volatile("" : "=a"(r) : "0"(t));
    return r;
}
// Use-side identity that KEEPS the value in AGPR (MFMA reads A from AGPR
// directly -> no v_accvgpr_read copies, unlike R6's "=v" aget).
__device__ __forceinline__ au4 ageta(au4 a) {
    au4 t;
    asm volatile("" : "=a"(t) : "0"(a));
    return t;
}

template <bool IS32>
__device__ __forceinline__ float ldf(const void* p, int i) {
    return IS32 ? ((const float*)p)[i] : bf2f(((const u16*)p)[i]);
}
template <bool IS32>
__device__ __forceinline__ u16 ldbf(const void* p, int i) {
    return IS32 ? f2bf(((const float*)p)[i]) : ((const u16*)p)[i];
}

__device__ __forceinline__ float lipswish(float x) {
    return 0.909f * x / (1.0f + __expf(-x));
}
__device__ __forceinline__ float tanh_fast(float x) {
    float e = __expf(2.0f * fabsf(x));   // may be +inf -> t = 1
    float t = 1.0f - 2.0f / (e + 1.0f);
    return copysignf(t, x);
}

struct __align__(16) SMem {
    u32 vW0p[WID][33];    // pairs of bf16 along K (65 -> 33 pairs, last hi=0)
    u32 cW0p[WID][33];
    u32 vW1p[WID][65];    // 64 pairs + 1 pad column
    u32 cW1p[WID][65];
    u32 vW2p[HDIM][65];
    float vb0[WID], vb1[WID], vb2[HDIM], vsc[HDIM];
    float cb0[WID], cb1[WID];
    float cb2[HN];
    float csc[HN];
    float roW[8][HDIM];
    float rob[8];
    float tsb[1028];
    float x[BB][68];      // [t, y(64), 0pad]; stride 68 keeps rows 16B-aligned
    float h1[2][BB][WID];
    float h2v[BB][WID];   // drift hidden-2 (fp32, VALU path)
    __align__(16) u16 hb16[BB][WID];   // diffusion hidden-2, bf16 hi (MFMA B)
    __align__(16) u16 hlo16[BB][WID];  // diffusion hidden-2, bf16 lo residual
    float yb[BB][HDIM];
    float fdt[BB][HDIM];
    float g0b[BB][HDIM];
    float gs[BB][HDIM];
    __align__(16) float dwb[BB][NZ];
};

__device__ __forceinline__ float dot64p(const u32* __restrict__ Wp, const float2* __restrict__ xp) {
    float a0 = 0.f, a1 = 0.f, a2 = 0.f, a3 = 0.f;
    #pragma unroll
    for (int kk = 0; kk < 64; kk += 4) {
        u32 w0 = Wp[kk], w1 = Wp[kk+1], w2 = Wp[kk+2], w3 = Wp[kk+3];
        float2 x0 = xp[kk], x1 = xp[kk+1], x2 = xp[kk+2], x3 = xp[kk+3];
        a0 = fmaf(lo16(w0), x0.x, fmaf(hi16(w0), x0.y, a0));
        a1 = fmaf(lo16(w1), x1.x, fmaf(hi16(w1), x1.y, a1));
        a2 = fmaf(lo16(w2), x2.x, fmaf(hi16(w2), x2.y, a2));
        a3 = fmaf(lo16(w3), x3.x, fmaf(hi16(w3), x3.y, a3));
    }
    return (a0 + a1) + (a2 + a3);
}

__device__ __forceinline__ float dot33p(const u32* __restrict__ Wp, const float2* __restrict__ xp) {
    float a0 = 0.f, a1 = 0.f, a2 = 0.f, a3 = 0.f;
    #pragma unroll
    for (int kk = 0; kk < 32; kk += 4) {
        u32 w0 = Wp[kk], w1 = Wp[kk+1], w2 = Wp[kk+2], w3 = Wp[kk+3];
        float2 x0 = xp[kk], x1 = xp[kk+1], x2 = xp[kk+2], x3 = xp[kk+3];
        a0 = fmaf(lo16(w0), x0.x, fmaf(hi16(w0), x0.y, a0));
        a1 = fmaf(lo16(w1), x1.x, fmaf(hi16(w1), x1.y, a1));
        a2 = fmaf(lo16(w2), x2.x, fmaf(hi16(w2), x2.y, a2));
        a3 = fmaf(lo16(w3), x3.x, fmaf(hi16(w3), x3.y, a3));
    }
    u32 wl = Wp[32]; float2 xv = xp[32];
    a0 = fmaf(lo16(wl), xv.x, fmaf(hi16(wl), xv.y, a0));
    return (a0 + a1) + (a2 + a3);
}

// MFMA big layer: C[1024 rows, 16 cols(2 samples used)] = W[1024,128] x h[128,*].
// Wave w owns rows 128w..128w+127 as 32 A-fragments in AGPRs (a[r*4+t]:
// row-tile r, K-tile t; lane: m=lane&15, k=8*(lane>>4)+j).
// B = diffusion h split hi+lo bf16 (fp32-accurate). D tile rows 16r..16r+15
// are exactly noise dims 0..15 of output h-index 8w+r -> per-tile reduction.
__device__ __forceinline__ void big_layer(SMem& sm, const au4 (&a)[32], int tid) {
    const int lane = tid & 63, w = tid >> 6;
    const int n = lane & 15, qq = lane >> 4;
    const int ns = n & 1;   // cols >=2 duplicate col n&1 (finite, discarded)
    bf16x8 bhi[4], blo[4];
    #pragma unroll
    for (int t = 0; t < 4; ++t) {
        uint4 h = *(const uint4*)&sm.hb16[ns][32 * t + 8 * qq];
        uint4 l = *(const uint4*)&sm.hlo16[ns][32 * t + 8 * qq];
        bhi[t] = __builtin_bit_cast(bf16x8, h);
        blo[t] = __builtin_bit_cast(bf16x8, l);
    }
    const float4 dw4 = *(const float4*)&sm.dwb[ns][4 * qq];
    #pragma unroll
    for (int r = 0; r < 8; ++r) {
        fx4 ah = {0.f, 0.f, 0.f, 0.f};
        fx4 al = {0.f, 0.f, 0.f, 0.f};
        #pragma unroll
        for (int t = 0; t < 4; ++t) {
            bf16x8 af = __builtin_bit_cast(bf16x8, ageta(a[r * 4 + t]));
            ah = __builtin_amdgcn_mfma_f32_16x16x32_bf16(af, bhi[t], ah, 0, 0, 0);
            al = __builtin_amdgcn_mfma_f32_16x16x32_bf16(af, blo[t], al, 0, 0, 0);
        }
        const int grb = 128 * w + 16 * r + 4 * qq;   // D rows: grb..grb+3 (reg)
        const float4 cb4 = *(const float4*)&sm.cb2[grb];
        const float4 cs4 = *(const float4*)&sm.csc[grb];
        float v;
        v =          tanh_fast(ah.x + al.x + cb4.x) * cs4.x * dw4.x;
        v = fmaf(tanh_fast(ah.y + al.y + cb4.y) * cs4.y, dw4.y, v);
        v = fmaf(tanh_fast(ah.z + al.z + cb4.z) * cs4.z, dw4.z, v);
        v = fmaf(tanh_fast(ah.w + al.w + cb4.w) * cs4.w, dw4.w, v);
        v += __shfl_xor(v, 16);   // reduce over the 4 quads (same n)
        v += __shfl_xor(v, 32);
        if (lane < 2) sm.gs[lane][8 * w + r] = v;   // lane0: n=0,q=0; lane1: n=1
    }
}

template <bool IS32>
__device__ __forceinline__ void stage_dw(SMem& sm, const uint4& d, int q, float sdt) {
    if (IS32) {
        const float* pf = (const float*)&d;
        int f = q * 4;
        #pragma unroll
        for (int k = 0; k < 4; ++k)
            sm.dwb[(f + k) >> 4][(f + k) & 15] = pf[k] * sdt;
    } else {
        int f = q * 8;
        u32 u0 = d.x, u1 = d.y, u2 = d.z, u3 = d.w;
        sm.dwb[(f    ) >> 4][(f    ) & 15] = lo16(u0) * sdt;
        sm.dwb[(f + 1) >> 4][(f + 1) & 15] = hi16(u0) * sdt;
        sm.dwb[(f + 2) >> 4][(f + 2) & 15] = lo16(u1) * sdt;
        sm.dwb[(f + 3) >> 4][(f + 3) & 15] = hi16(u1) * sdt;
        sm.dwb[(f + 4) >> 4][(f + 4) & 15] = lo16(u2) * sdt;
        sm.dwb[(f + 5) >> 4][(f + 5) & 15] = hi16(u2) * sdt;
        sm.dwb[(f + 6) >> 4][(f + 6) & 15] = lo16(u3) * sdt;
        sm.dwb[(f + 7) >> 4][(f + 7) & 15] = hi16(u3) * sdt;
    }
}

template <bool IS32>
__device__ __forceinline__ void write_out(void* out, size_t idx, const float* v8) {
    if (IS32) {
        float4 o0, o1;
        o0.x = v8[0]; o0.y = v8[1]; o0.z = v8[2]; o0.w = v8[3];
        o1.x = v8[4]; o1.y = v8[5]; o1.z = v8[6]; o1.w = v8[7];
        ((float4*)out)[idx * 2]     = o0;
        ((float4*)out)[idx * 2 + 1] = o1;
    } else {
        uint4 o;
        o.x = pk(v8[0], v8[1]);
        o.y = pk(v8[2], v8[3]);
        o.z = pk(v8[4], v8[5]);
        o.w = pk(v8[6], v8[7]);
        ((uint4*)out)[idx] = o;
    }
}

template <bool IS32>
__device__ __forceinline__ void
sde_run(SMem& sm,
        const void* ts,  const void* z0,  const void* dW,
        const void* iW0, const void* ib0, const void* iW1, const void* ib1,
        const void* iW2, const void* ib2,
        const void* vW0, const void* vb0, const void* vW1, const void* vb1,
        const void* vW2, const void* vb2, const void* vsc,
        const void* cW0, const void* cb0, const void* cW1, const void* cb1,
        const void* cW2, const void* cb2, const void* csc,
        const void* roW, const void* rob, void* out,
        int tid, int bid)
{
    const int lane = tid & 63, wv = tid >> 6;

    // ---- cW2 -> 32 MFMA A-fragments per lane, pinned in AGPRs ----
    au4 a[32];
    {
        const int mm = lane & 15, qq = lane >> 4;
        #pragma unroll
        for (int r = 0; r < 8; ++r) {
            #pragma unroll
            for (int t = 0; t < 4; ++t) {
                const int gr = 128 * wv + 16 * r + mm;
                const int k0 = 32 * t + 8 * qq;
                uint4 v;
                if (!IS32) {
                    v = *(const uint4*)((const u16*)cW2 + (size_t)gr * WID + k0);
                } else {
                    const float* base = (const float*)cW2 + (size_t)gr * WID + k0;
                    float4 A0 = *(const float4*)base;
                    float4 A1 = *(const float4*)(base + 4);
                    v.x = pk(A0.x, A0.y); v.y = pk(A0.z, A0.w);
                    v.z = pk(A1.x, A1.y); v.w = pk(A1.z, A1.w);
                }
                a[r * 4 + t] = apin(v);
            }
        }
    }

    // ---- stage weights into LDS as packed bf16 pairs ----
    for (int idx = tid; idx < WID * 33; idx += NTHREADS) {
        int j = idx / 33, kk = idx - j * 33;
        int k0 = 2 * kk;
        u32 lo, hi;
        lo = ldbf<IS32>(vW0, j * IND + k0);
        hi = (k0 + 1 < IND) ? (u32)ldbf<IS32>(vW0, j * IND + k0 + 1) : 0u;
        sm.vW0p[j][kk] = lo | (hi << 16);
        lo = ldbf<IS32>(cW0, j * IND + k0);
        hi = (k0 + 1 < IND) ? (u32)ldbf<IS32>(cW0, j * IND + k0 + 1) : 0u;
        sm.cW0p[j][kk] = lo | (hi << 16);
    }
    for (int idx = tid; idx < WID * 65; idx += NTHREADS) {
        int j = idx / 65, kk = idx - j * 65;
        u32 v = 0, c = 0;
        if (kk < 64) {
            int k0 = 2 * kk;
            v = (u32)ldbf<IS32>(vW1, j * WID + k0) | ((u32)ldbf<IS32>(vW1, j * WID + k0 + 1) << 16);
            c = (u32)ldbf<IS32>(cW1, j * WID + k0) | ((u32)ldbf<IS32>(cW1, j * WID + k0 + 1) << 16);
        }
        sm.vW1p[j][kk] = v;
        sm.cW1p[j][kk] = c;
    }
    for (int idx = tid; idx < HDIM * 65; idx += NTHREADS) {
        int j = idx / 65, kk = idx - j * 65;
        u32 v = 0;
        if (kk < 64) {
            int k0 = 2 * kk;
            v = (u32)ldbf<IS32>(vW2, j * WID + k0) | ((u32)ldbf<IS32>(vW2, j * WID + k0 + 1) << 16);
        }
        sm.vW2p[j][kk] = v;
    }
    if (tid < WID) {
        sm.vb0[tid] = ldf<IS32>(vb0, tid); sm.vb1[tid] = ldf<IS32>(vb1, tid);
        sm.cb0[tid] = ldf<IS32>(cb0, tid); sm.cb1[tid] = ldf<IS32>(cb1, tid);
        if (tid < HDIM) { sm.vb2[tid] = ldf<IS32>(vb2, tid); sm.vsc[tid] = ldf<IS32>(vsc, tid); }
        if (tid < 8) sm.rob[tid] = ldf<IS32>(rob, tid);
    }
    for (int i = tid; i < HN; i += NTHREADS) {
        sm.cb2[i] = ldf<IS32>(cb2, i);
        sm.csc[i] = ldf<IS32>(csc, i);
    }
    { int d = tid >> 6, i2 = tid & 63; sm.roW[d][i2] = ldf<IS32>(roW, tid); }
    for (int i = tid; i < TPTS; i += NTHREADS) sm.tsb[i] = ldf<IS32>(ts, i);

    // prefetch dW for step 0
    uint4 dwpref;
    if (tid >= 128 && tid < 136) {
        int q = tid - 128;
        if (IS32)       dwpref = ((const uint4*)dW)[(size_t)bid * 8 + q];       // 8 x float4
        else if (q < 4) dwpref = ((const uint4*)dW)[(size_t)bid * 4 + q];       // 4 x bf16x8
    }

    __syncthreads();

    const float dt  = sm.tsb[1] - sm.tsb[0];
    const float sdt = sqrtf(dt);

    if (tid >= 128 && tid < 136) {
        int q = tid - 128;
        if (IS32 || q < 4) stage_dw<IS32>(sm, dwpref, q, sdt);
    }

    // ---- initial MLP (relu, relu, identity): z0(8) -> 128 -> 128 -> y0(64) ----
    if (tid < 256) {   // I1
        int b = tid >> 7, j = tid & 127;
        float acc = ldf<IS32>(ib0, j);
        #pragma unroll
        for (int k = 0; k < 8; ++k)
            acc = fmaf(ldf<IS32>(iW0, j * 8 + k), ldf<IS32>(z0, (bid * BB + b) * 8 + k), acc);
        sm.h1[0][b][j] = fmaxf(acc, 0.0f);
    }
    __syncthreads();
    if (tid < 256) {   // I2
        int b = tid >> 7, j = tid & 127;
        float acc = ldf<IS32>(ib1, j);
        for (int k = 0; k < WID; ++k)
            acc = fmaf(ldf<IS32>(iW1, j * WID + k), sm.h1[0][b][k], acc);
        sm.h2v[b][j] = fmaxf(acc, 0.0f);
    }
    __syncthreads();
    if (tid < 128) {   // I3: y0, x init, t=0 readout
        int b = tid >> 6, i = tid & 63;
        float y0 = ldf<IS32>(ib2, i);
        for (int k = 0; k < WID; ++k)
            y0 = fmaf(ldf<IS32>(iW2, i * WID + k), sm.h2v[b][k], y0);
        sm.yb[b][i] = y0;
        sm.x[b][1 + i] = y0;
        if (i == 0) {
            sm.x[b][0] = sm.tsb[0];
            sm.x[b][65] = 0.0f; sm.x[b][66] = 0.0f; sm.x[b][67] = 0.0f;
        }
        float acc[8];
        #pragma unroll
        for (int d = 0; d < 8; ++d) acc[d] = sm.roW[d][i] * y0;
        #pragma unroll
        for (int m = 1; m < 64; m <<= 1) {
            #pragma unroll
            for (int d = 0; d < 8; ++d) acc[d] += __shfl_xor(acc[d], m);
        }
        if (i == 0) {
            float v8[8];
            #pragma unroll
            for (int d = 0; d < 8; ++d) v8[d] = acc[d] + sm.rob[d];
            write_out<IS32>(out, (size_t)(bid * BB + b) * TPTS, v8);
        }
    }
    __syncthreads();

    // ---- main scan: 1024 Euler-Heun steps ----
    for (int s = 0; s < STEPS; ++s) {
        if (s + 1 < STEPS && tid >= 128 && tid < 136) {
            int q = tid - 128;
            if (IS32)       dwpref = ((const uint4*)dW)[(size_t)(s + 1) * 2048 + bid * 8 + q];
            else if (q < 4) dwpref = ((const uint4*)dW)[(size_t)(s + 1) * 1024 + bid * 4 + q];
        }
        // P2: fused L0 for drift(v=0) and diffusion(c=1), input x=[t,y]
        {
            const int mlp = tid >> 8, b = (tid >> 7) & 1, j = tid & 127;
            const u32* Wp = mlp ? sm.cW0p[j] : sm.vW0p[j];
            const float bias = mlp ? sm.cb0[j] : sm.vb0[j];
            float acc = bias + dot33p(Wp, (const float2*)sm.x[b]);
            sm.h1[mlp][b][j] = lipswish(acc);
        }
        __syncthreads();
        // P3: fused L1; diffusion side emits bf16 hi/lo for MFMA B
        {
            const int mlp = tid >> 8, b = (tid >> 7) & 1, j = tid & 127;
            const u32* Wp = mlp ? sm.cW1p[j] : sm.vW1p[j];
            const float bias = mlp ? sm.cb1[j] : sm.vb1[j];
            float h = lipswish(bias + dot64p(Wp, (const float2*)sm.h1[mlp][b]));
            if (mlp == 0) {
                sm.h2v[b][j] = h;
            } else {
                u16 hi = f2bf(h);
                sm.hb16[b][j] = hi;
                sm.hlo16[b][j] = f2bf(h - bf2f(hi));
            }
        }
        __syncthreads();
        // P4: diffusion big layer eval 1 (MFMA) -> gs = g0
        big_layer(sm, a, tid);
        __syncthreads();
        // P5: x' = y + g0 (waves 0-1) | drift L2 -> fdt (waves 2-3)
        if (tid < 128) {
            int b = tid >> 6, i = tid & 63;
            float g0 = sm.gs[b][i];
            sm.g0b[b][i] = g0;
            sm.x[b][1 + i] = sm.yb[b][i] + g0;
        } else if (tid < 256) {
            int q = tid - 128, b = q >> 6, j = q & 63;
            float acc = sm.vb2[j] + dot64p(sm.vW2p[j], (const float2*)sm.h2v[b]);
            sm.fdt[b][j] = sm.vsc[j] * tanh_fast(acc) * dt;
        }
        __syncthreads();
        // P6: diffusion L0 on x'
        if (tid < 256) {
            int b = tid >> 7, j = tid & 127;
            float acc = sm.cb0[j] + dot33p(sm.cW0p[j], (const float2*)sm.x[b]);
            sm.h1[1][b][j] = lipswish(acc);
        }
        __syncthreads();
        // P7: diffusion L1 -> bf16 hi/lo
        if (tid < 256) {
            int b = tid >> 7, j = tid & 127;
            float h = lipswish(sm.cb1[j] + dot64p(sm.cW1p[j], (const float2*)sm.h1[1][b]));
            u16 hi = f2bf(h);
            sm.hb16[b][j] = hi;
            sm.hlo16[b][j] = f2bf(h - bf2f(hi));
        }
        __syncthreads();
        // P8: diffusion big layer eval 2 (MFMA) -> gs = g1
        big_layer(sm, a, tid);
        __syncthreads();
        // P9: y1 = y + f0*dt + 0.5*(g0+g1); readout; stage next x and dw
        if (tid < 128) {
            int b = tid >> 6, i = tid & 63;
            float y1 = sm.yb[b][i] + sm.fdt[b][i] + 0.5f * (sm.g0b[b][i] + sm.gs[b][i]);
            sm.yb[b][i] = y1;
            sm.x[b][1 + i] = y1;
            if (i == 0) sm.x[b][0] = sm.tsb[s + 1];
            float acc[8];
            #pragma unroll
            for (int d = 0; d < 8; ++d) acc[d] = sm.roW[d][i] * y1;
            #pragma unroll
            for (int m = 1; m < 64; m <<= 1) {
                #pragma unroll
                for (int d = 0; d < 8; ++d) acc[d] += __shfl_xor(acc[d], m);
            }
            if (i == 0) {
                float v8[8];
                #pragma unroll
                for (int d = 0; d < 8; ++d) v8[d] = acc[d] + sm.rob[d];
                write_out<IS32>(out, (size_t)(bid * BB + b) * TPTS + (s + 1), v8);
            }
        } else if (tid >= 128 && tid < 136 && s + 1 < STEPS) {
            int q = tid - 128;
            if (IS32 || q < 4) stage_dw<IS32>(sm, dwpref, q, sdt);
        }
        __syncthreads();
    }
}

__global__ void
__attribute__((amdgpu_flat_work_group_size(NTHREADS, NTHREADS), amdgpu_waves_per_eu(2, 2)))
sde_kernel(const void* __restrict__ ts,  const void* __restrict__ z0,  const void* __restrict__ dW,
           const void* __restrict__ iW0, const void* __restrict__ ib0, const void* __restrict__ iW1,
           const void* __restrict__ ib1, const void* __restrict__ iW2, const void* __restrict__ ib2,
           const void* __restrict__ vW0, const void* __restrict__ vb0, const void* __restrict__ vW1,
           const void* __restrict__ vb1, const void* __restrict__ vW2, const void* __restrict__ vb2,
           const void* __restrict__ vsc, const void* __restrict__ cW0, const void* __restrict__ cb0,
           const void* __restrict__ cW1, const void* __restrict__ cb1, const void* __restrict__ cW2,
           const void* __restrict__ cb2, const void* __restrict__ csc, const void* __restrict__ roW,
           const void* __restrict__ rob, void* __restrict__ out)
{
    __shared__ SMem sm;
    const int tid = threadIdx.x;
    const int bid = blockIdx.x;

    // dtype detection: u16 word #1 of ts. bf16: bf16(1/1024)=0x3A80 != 0.
    // fp32: high half of 0.0f == 0.
    const bool is32 = (((const u16*)ts)[1] == 0);

    if (is32) {
        sde_run<true>(sm, ts, z0, dW, iW0, ib0, iW1, ib1, iW2, ib2,
                      vW0, vb0, vW1, vb1, vW2, vb2, vsc,
                      cW0, cb0, cW1, cb1, cW2, cb2, csc, roW, rob, out, tid, bid);
    } else {
        sde_run<false>(sm, ts, z0, dW, iW0, ib0, iW1, ib1, iW2, ib2,
                       vW0, vb0, vW1, vb1, vW2, vb2, vsc,
                       cW0, cb0, cW1, cb1, cW2, cb2, csc, roW, rob, out, tid, bid);
    }
}

extern "C" void kernel_launch(void* const* d_in, const int* in_sizes, int n_in,
                              void* d_out, int out_size, void* d_ws, size_t ws_size,
                              hipStream_t stream) {
    (void)in_sizes; (void)n_in; (void)d_ws; (void)ws_size; (void)out_size;
    hipLaunchKernelGGL(sde_kernel, dim3(NBLOCKS), dim3(NTHREADS), 0, stream,
                       d_in[0], d_in[1], d_in[2], d_in[3], d_in[4], d_in[5], d_in[6],
                       d_in[7], d_in[8], d_in[9], d_in[10], d_in[11], d_in[12], d_in[13],
                       d_in[14], d_in[15], d_in[16], d_in[17], d_in[18], d_in[19], d_in[20],
                       d_in[21], d_in[22], d_in[23], d_in[24], d_out);
}

// Round 8
// 7490.388 us; speedup vs baseline: 3.5405x; 2.0764x over previous
//
#include <hip/hip_runtime.h>

typedef unsigned short u16;
typedef unsigned int   u32;
typedef __attribute__((ext_vector_type(4))) unsigned int au4;
typedef __attribute__((ext_vector_type(4))) float fx4;
typedef __attribute__((ext_vector_type(8))) __bf16 bf16x8;

#define NTHREADS 512
#define NBLOCKS  256
#define BB       2
#define STEPS    1024
#define TPTS     1025
#define HDIM     64
#define NZ       16
#define WID      128
#define IND      65
#define HN       1024

__device__ __forceinline__ float bf2f(u16 v) { return __uint_as_float(((u32)v) << 16); }
__device__ __forceinline__ u16 f2bf(float f) {
    u32 u = __float_as_uint(f);
    return (u16)((u + 0x7fffu + ((u >> 16) & 1u)) >> 16);
}
__device__ __forceinline__ float lo16(u32 u) { return __uint_as_float(u << 16); }
__device__ __forceinline__ float hi16(u32 u) { return __uint_as_float(u & 0xffff0000u); }
__device__ __forceinline__ u32 pk(float a, float b) {
    return (u32)f2bf(a) | ((u32)f2bf(b) << 16);
}

// AGPR pinning (validated R6/R7): "=a" def homes values in AGPRs so the
// scheduler cannot sink the weight loads into the step loop; ageta keeps the
// value in the 'a' class so MFMA consumes it directly (no accvgpr_read).
__device__ __forceinline__ au4 apin(uint4 v) {
    au4 t; t.x = v.x; t.y = v.y; t.z = v.z; t.w = v.w;
    au4 r;
    asm volatile("" : "=a"(r) : "0"(t));
    return r;
}
__device__ __forceinline__ au4 ageta(au4 a) {
    au4 t;
    asm volatile("" : "=a"(t) : "0"(a));
    return t;
}

template <bool IS32>
__device__ __forceinline__ float ldf(const void* p, int i) {
    return IS32 ? ((const float*)p)[i] : bf2f(((const u16*)p)[i]);
}
template <bool IS32>
__device__ __forceinline__ u16 ldbf(const void* p, int i) {
    return IS32 ? f2bf(((const float*)p)[i]) : ((const u16*)p)[i];
}

__device__ __forceinline__ float lipswish(float x) {
    return 0.909f * x / (1.0f + __expf(-x));
}
__device__ __forceinline__ float tanh_fast(float x) {
    float e = __expf(2.0f * fabsf(x));   // may be +inf -> t = 1
    float t = 1.0f - 2.0f / (e + 1.0f);
    return copysignf(t, x);
}
__device__ __forceinline__ void split_bf(float v, u16& hi, u16& lo) {
    hi = f2bf(v);
    lo = f2bf(v - bf2f(hi));
}

struct __align__(16) SMem {
    // MFMA B operands (activations), bf16 hi + lo residual
    __align__(16) u16 bxh[BB][96],  bxl[BB][96];       // x=[t,y,pad] per sample
    __align__(16) u16 bh1h[2][BB][WID], bh1l[2][BB][WID];
    __align__(16) u16 bh2vh[BB][WID], bh2vl[BB][WID];  // drift hidden2
    __align__(16) u16 bh2ch[BB][WID], bh2cl[BB][WID];  // diffusion hidden2
    // drift L2 weights, frag-major (lane-contiguous b128 -> conflict-free)
    __align__(16) u16 vW2F[4][4][64][8];               // [rt][kt][lane][8]
    // raw MFMA outputs (2 real columns)
    __align__(16) float accL0[BB][256];
    __align__(16) float accL1[BB][256];
    __align__(16) float accL2v[BB][HDIM];
    __align__(16) float accBig[BB][HN];
    // constants
    __align__(16) float b0s[256], b1s[256], vb2[HDIM], vsc[HDIM];
    __align__(16) float cb2[HN], csc[HN];
    __align__(16) float roW[8][HDIM];
    __align__(16) float rob[8];
    __align__(16) float tsb[1028];
    // state
    __align__(16) float yb[BB][HDIM], g0b[BB][HDIM], fdt[BB][HDIM];
    __align__(16) float dwb[BB][NZ];
};

__device__ __forceinline__ bf16x8 bfrag(const u16* p) {
    return __builtin_bit_cast(bf16x8, *(const uint4*)p);
}
// acc += A * (Bhi + Blo)  via two chained MFMAs, A straight from AGPR
__device__ __forceinline__ fx4 mf2(au4 a, bf16x8 bh, bf16x8 bl, fx4 acc) {
    bf16x8 af = __builtin_bit_cast(bf16x8, ageta(a));
    acc = __builtin_amdgcn_mfma_f32_16x16x32_bf16(af, bh, acc, 0, 0, 0);
    acc = __builtin_amdgcn_mfma_f32_16x16x32_bf16(af, bl, acc, 0, 0, 0);
    return acc;
}

template <bool IS32>
__device__ __forceinline__ uint4 load8(const void* src, int row, int stride, int k0, int Klim) {
    u16 e[8];
    #pragma unroll
    for (int j = 0; j < 8; ++j) {
        int k = k0 + j;
        e[j] = (k < Klim) ? ldbf<IS32>(src, row * stride + k) : (u16)0;
    }
    uint4 v;
    v.x = (u32)e[0] | ((u32)e[1] << 16);
    v.y = (u32)e[2] | ((u32)e[3] << 16);
    v.z = (u32)e[4] | ((u32)e[5] << 16);
    v.w = (u32)e[6] | ((u32)e[7] << 16);
    return v;
}

template <bool IS32>
__device__ __forceinline__ void stage_dw(SMem& sm, const uint4& d, int q, float sdt) {
    if (IS32) {
        const float* pf = (const float*)&d;
        int f = q * 4;
        #pragma unroll
        for (int k = 0; k < 4; ++k)
            sm.dwb[(f + k) >> 4][(f + k) & 15] = pf[k] * sdt;
    } else {
        int f = q * 8;
        u32 u0 = d.x, u1 = d.y, u2 = d.z, u3 = d.w;
        sm.dwb[(f    ) >> 4][(f    ) & 15] = lo16(u0) * sdt;
        sm.dwb[(f + 1) >> 4][(f + 1) & 15] = hi16(u0) * sdt;
        sm.dwb[(f + 2) >> 4][(f + 2) & 15] = lo16(u1) * sdt;
        sm.dwb[(f + 3) >> 4][(f + 3) & 15] = hi16(u1) * sdt;
        sm.dwb[(f + 4) >> 4][(f + 4) & 15] = lo16(u2) * sdt;
        sm.dwb[(f + 5) >> 4][(f + 5) & 15] = hi16(u2) * sdt;
        sm.dwb[(f + 6) >> 4][(f + 6) & 15] = lo16(u3) * sdt;
        sm.dwb[(f + 7) >> 4][(f + 7) & 15] = hi16(u3) * sdt;
    }
}

template <bool IS32>
__device__ __forceinline__ void write_out(void* out, size_t idx, const float* v8) {
    if (IS32) {
        float4 o0, o1;
        o0.x = v8[0]; o0.y = v8[1]; o0.z = v8[2]; o0.w = v8[3];
        o1.x = v8[4]; o1.y = v8[5]; o1.z = v8[6]; o1.w = v8[7];
        ((float4*)out)[idx * 2]     = o0;
        ((float4*)out)[idx * 2 + 1] = o1;
    } else {
        uint4 o;
        o.x = pk(v8[0], v8[1]);
        o.y = pk(v8[2], v8[3]);
        o.z = pk(v8[4], v8[5]);
        o.w = pk(v8[6], v8[7]);
        ((uint4*)out)[idx] = o;
    }
}

template <bool IS32>
__device__ __forceinline__ void
sde_run(SMem& sm,
        const void* ts,  const void* z0,  const void* dW,
        const void* iW0, const void* ib0, const void* iW1, const void* ib1,
        const void* iW2, const void* ib2,
        const void* vW0, const void* vb0, const void* vW1, const void* vb1,
        const void* vW2, const void* vb2, const void* vsc,
        const void* cW0, const void* cb0, const void* cW1, const void* cb1,
        const void* cW2, const void* cb2, const void* csc,
        const void* roW, const void* rob, void* out,
        int tid, int bid)
{
    const int lane = tid & 63, wv = tid >> 6;
    const int mm = lane & 15, qq = lane >> 4;
    const int nn = mm;    // B/D column index within tile

    // ---- weight A-fragments -> AGPRs (184 u32/thread) ----
    au4 a0[6];    // stacked [vW0;cW0] 256x65(pad96): wave rt {2wv,2wv+1} x kt{0..2}
    au4 a1[8];    // waves0-3: vW1; waves4-7: cW1: rt{2wl,2wl+1} x kt{0..3}
    au4 ab[32];   // cW2 1024x128: wave rows 128wv..+127: r8{0..7} x kt{0..3}
    #pragma unroll
    for (int rtl = 0; rtl < 2; ++rtl) {
        int grow = 16 * (2 * wv + rtl) + mm;
        const void* src = (grow < 128) ? vW0 : cW0;
        int r = grow & 127;
        #pragma unroll
        for (int kt = 0; kt < 3; ++kt)
            a0[rtl * 3 + kt] = apin(load8<IS32>(src, r, IND, 32 * kt + 8 * qq, IND));
    }
    {
        const void* src = (wv < 4) ? vW1 : cW1;
        int wl = wv & 3;
        #pragma unroll
        for (int rtl = 0; rtl < 2; ++rtl) {
            int r = 16 * (2 * wl + rtl) + mm;
            #pragma unroll
            for (int kt = 0; kt < 4; ++kt)
                a1[rtl * 4 + kt] = apin(load8<IS32>(src, r, WID, 32 * kt + 8 * qq, WID));
        }
    }
    #pragma unroll
    for (int r8 = 0; r8 < 8; ++r8) {
        int r = 128 * wv + 16 * r8 + mm;
        #pragma unroll
        for (int kt = 0; kt < 4; ++kt)
            ab[r8 * 4 + kt] = apin(load8<IS32>(cW2, r, WID, 32 * kt + 8 * qq, WID));
    }

    // ---- LDS staging ----
    // drift W2 in frag-major LDS: slot = ((rt*4+kt)*64+lane)
    for (int slot = tid; slot < 1024; slot += NTHREADS) {
        int rt = slot >> 8, kt = (slot >> 6) & 3, l = slot & 63;
        int m = l & 15, q = l >> 4;
        uint4 v = load8<IS32>(vW2, 16 * rt + m, WID, 32 * kt + 8 * q, WID);
        *(uint4*)&sm.vW2F[rt][kt][l][0] = v;
    }
    if (tid < 256) {
        sm.b0s[tid] = (tid < 128) ? ldf<IS32>(vb0, tid) : ldf<IS32>(cb0, tid - 128);
        sm.b1s[tid] = (tid < 128) ? ldf<IS32>(vb1, tid) : ldf<IS32>(cb1, tid - 128);
    } else if (tid < 320) {
        int i = tid - 256;
        sm.vb2[i] = ldf<IS32>(vb2, i);
        sm.vsc[i] = ldf<IS32>(vsc, i);
    } else if (tid < 328) {
        sm.rob[tid - 320] = ldf<IS32>(rob, tid - 320);
    } else if (tid >= 384 && tid < 448) {
        // zero x pads k=65..95 (A pads are 0 but 0*NaN(junk LDS) = NaN)
        int b = (tid - 384) >> 5, k = 65 + ((tid - 384) & 31);
        if (k < 96) { sm.bxh[b][k] = 0; sm.bxl[b][k] = 0; }
    }
    for (int i = tid; i < HN; i += NTHREADS) {
        sm.cb2[i] = ldf<IS32>(cb2, i);
        sm.csc[i] = ldf<IS32>(csc, i);
    }
    { int d = tid >> 6, i2 = tid & 63; sm.roW[d][i2] = ldf<IS32>(roW, tid); }
    for (int i = tid; i < TPTS; i += NTHREADS) sm.tsb[i] = ldf<IS32>(ts, i);

    // dW prefetch for step 0
    uint4 dwpref;
    if (tid >= 128 && tid < 136) {
        int q = tid - 128;
        if (IS32)       dwpref = ((const uint4*)dW)[(size_t)bid * 8 + q];
        else if (q < 4) dwpref = ((const uint4*)dW)[(size_t)bid * 4 + q];
    }
    __syncthreads();

    const float dt  = sm.tsb[1] - sm.tsb[0];
    const float sdt = sqrtf(dt);
    if (tid >= 128 && tid < 136) {
        int q = tid - 128;
        if (IS32 || q < 4) stage_dw<IS32>(sm, dwpref, q, sdt);
    }

    // ---- initial MLP (VALU, once): z0 -> 128 -> 128 -> y0 ----
    if (tid < 256) {
        int b = tid >> 7, j = tid & 127;
        float acc = ldf<IS32>(ib0, j);
        #pragma unroll
        for (int k = 0; k < 8; ++k)
            acc = fmaf(ldf<IS32>(iW0, j * 8 + k), ldf<IS32>(z0, (bid * BB + b) * 8 + k), acc);
        sm.accL0[b][j] = fmaxf(acc, 0.0f);
    }
    __syncthreads();
    if (tid < 256) {
        int b = tid >> 7, j = tid & 127;
        float acc = ldf<IS32>(ib1, j);
        for (int k = 0; k < WID; ++k)
            acc = fmaf(ldf<IS32>(iW1, j * WID + k), sm.accL0[b][k], acc);
        sm.accL1[b][j] = fmaxf(acc, 0.0f);
    }
    __syncthreads();
    if (tid < 128) {
        int b = tid >> 6, i = tid & 63;
        float y0 = ldf<IS32>(ib2, i);
        for (int k = 0; k < WID; ++k)
            y0 = fmaf(ldf<IS32>(iW2, i * WID + k), sm.accL1[b][k], y0);
        sm.yb[b][i] = y0;
        u16 hi, lo; split_bf(y0, hi, lo);
        sm.bxh[b][1 + i] = hi; sm.bxl[b][1 + i] = lo;
        if (i == 0) {
            u16 thi, tlo; split_bf(sm.tsb[0], thi, tlo);
            sm.bxh[b][0] = thi; sm.bxl[b][0] = tlo;
        }
    }
    __syncthreads();

    // ---- main scan ----
    for (int s = 0; s < STEPS; ++s) {
        // PA: L0 MFMA for both MLPs on x (all waves); stage dwb for this step (s>0)
        if (s > 0 && tid >= 128 && tid < 136) {
            int q = tid - 128;
            if (IS32 || q < 4) stage_dw<IS32>(sm, dwpref, q, sdt);
        }
        {
            bf16x8 bh[3], bl[3];
            #pragma unroll
            for (int kt = 0; kt < 3; ++kt) {
                bh[kt] = bfrag(&sm.bxh[nn & 1][32 * kt + 8 * qq]);
                bl[kt] = bfrag(&sm.bxl[nn & 1][32 * kt + 8 * qq]);
            }
            #pragma unroll
            for (int rtl = 0; rtl < 2; ++rtl) {
                fx4 acc = {0.f, 0.f, 0.f, 0.f};
                #pragma unroll
                for (int kt = 0; kt < 3; ++kt)
                    acc = mf2(a0[rtl * 3 + kt], bh[kt], bl[kt], acc);
                int rowb = 16 * (2 * wv + rtl) + 4 * qq;
                if (nn < 2) *(fx4*)&sm.accL0[nn][rowb] = acc;
            }
        }
        __syncthreads();
        // PB: activation L0 -> h1 (both mlps), 512 thr
        {
            int r = tid >> 1, c = tid & 1;
            float h = lipswish(sm.accL0[c][r] + sm.b0s[r]);
            u16 hi, lo; split_bf(h, hi, lo);
            int mlp = r >> 7, j = r & 127;
            sm.bh1h[mlp][c][j] = hi;
            sm.bh1l[mlp][c][j] = lo;
        }
        __syncthreads();
        // PC: L1 MFMA (waves0-3 drift, waves4-7 diffusion)
        {
            const u16* bhs = sm.bh1h[wv < 4 ? 0 : 1][0];
            const u16* bls = sm.bh1l[wv < 4 ? 0 : 1][0];
            bf16x8 bh[4], bl[4];
            #pragma unroll
            for (int kt = 0; kt < 4; ++kt) {
                bh[kt] = bfrag(&bhs[(nn & 1) * WID + 32 * kt + 8 * qq]);
                bl[kt] = bfrag(&bls[(nn & 1) * WID + 32 * kt + 8 * qq]);
            }
            int wl = wv & 3, base = (wv < 4) ? 0 : 128;
            #pragma unroll
            for (int rtl = 0; rtl < 2; ++rtl) {
                fx4 acc = {0.f, 0.f, 0.f, 0.f};
                #pragma unroll
                for (int kt = 0; kt < 4; ++kt)
                    acc = mf2(a1[rtl * 4 + kt], bh[kt], bl[kt], acc);
                int rowb = base + 16 * (2 * wl + rtl) + 4 * qq;
                if (nn < 2) *(fx4*)&sm.accL1[nn][rowb] = acc;
            }
        }
        __syncthreads();
        // PD: activation L1 -> h2v / h2c, 512 thr
        {
            int r = tid >> 1, c = tid & 1;
            float h = lipswish(sm.accL1[c][r] + sm.b1s[r]);
            u16 hi, lo; split_bf(h, hi, lo);
            if (r < 128) { sm.bh2vh[c][r] = hi;      sm.bh2vl[c][r] = lo; }
            else         { sm.bh2ch[c][r - 128] = hi; sm.bh2cl[c][r - 128] = lo; }
        }
        __syncthreads();
        // PE: big MFMA (all waves) + drift L2 (waves 0-3, A from LDS frag table)
        {
            bf16x8 bh[4], bl[4];
            #pragma unroll
            for (int kt = 0; kt < 4; ++kt) {
                bh[kt] = bfrag(&sm.bh2ch[nn & 1][32 * kt + 8 * qq]);
                bl[kt] = bfrag(&sm.bh2cl[nn & 1][32 * kt + 8 * qq]);
            }
            #pragma unroll
            for (int r8 = 0; r8 < 8; ++r8) {
                fx4 acc = {0.f, 0.f, 0.f, 0.f};
                #pragma unroll
                for (int kt = 0; kt < 4; ++kt)
                    acc = mf2(ab[r8 * 4 + kt], bh[kt], bl[kt], acc);
                int rowb = 128 * wv + 16 * r8 + 4 * qq;
                if (nn < 2) *(fx4*)&sm.accBig[nn][rowb] = acc;
            }
            if (wv < 4) {
                fx4 acc = {0.f, 0.f, 0.f, 0.f};
                #pragma unroll
                for (int kt = 0; kt < 4; ++kt) {
                    bf16x8 aw = bfrag(&sm.vW2F[wv][kt][lane][0]);
                    bf16x8 vh = bfrag(&sm.bh2vh[nn & 1][32 * kt + 8 * qq]);
                    bf16x8 vl = bfrag(&sm.bh2vl[nn & 1][32 * kt + 8 * qq]);
                    acc = __builtin_amdgcn_mfma_f32_16x16x32_bf16(aw, vh, acc, 0, 0, 0);
                    acc = __builtin_amdgcn_mfma_f32_16x16x32_bf16(aw, vl, acc, 0, 0, 0);
                }
                int rowb = 16 * wv + 4 * qq;
                if (nn < 2) *(fx4*)&sm.accL2v[nn][rowb] = acc;
            }
        }
        __syncthreads();
        // PF: eval-1 epilogue: g0 (4 tanh/thr), fdt (low 128), x' write
        {
            int p = tid >> 2, q4 = tid & 3;
            int b = p >> 6, h = p & 63;
            int rb = 16 * h + 4 * q4;
            fx4 acc = *(const fx4*)&sm.accBig[b][rb];
            float4 cb = *(const float4*)&sm.cb2[rb];
            float4 cs = *(const float4*)&sm.csc[rb];
            float4 dw = *(const float4*)&sm.dwb[b][4 * q4];
            float v;
            v  = tanh_fast(acc.x + cb.x) * cs.x * dw.x;
            v  = fmaf(tanh_fast(acc.y + cb.y) * cs.y, dw.y, v);
            v  = fmaf(tanh_fast(acc.z + cb.z) * cs.z, dw.z, v);
            v  = fmaf(tanh_fast(acc.w + cb.w) * cs.w, dw.w, v);
            v += __shfl_xor(v, 1);
            v += __shfl_xor(v, 2);
            if (tid < 128) {
                int b2 = tid >> 6, i = tid & 63;
                sm.fdt[b2][i] = sm.vsc[i] * tanh_fast(sm.accL2v[b2][i] + sm.vb2[i]) * dt;
            }
            if (q4 == 0) {
                sm.g0b[b][h] = v;
                float xp = sm.yb[b][h] + v;
                u16 hi, lo; split_bf(xp, hi, lo);
                sm.bxh[b][1 + h] = hi; sm.bxl[b][1 + h] = lo;
            }
        }
        __syncthreads();
        // PA2: diffusion L0 on x' (waves 4-7) | readout y_s (waves 0-1) | dW prefetch (wave 2)
        if (wv >= 4) {
            bf16x8 bh[3], bl[3];
            #pragma unroll
            for (int kt = 0; kt < 3; ++kt) {
                bh[kt] = bfrag(&sm.bxh[nn & 1][32 * kt + 8 * qq]);
                bl[kt] = bfrag(&sm.bxl[nn & 1][32 * kt + 8 * qq]);
            }
            #pragma unroll
            for (int rtl = 0; rtl < 2; ++rtl) {
                fx4 acc = {0.f, 0.f, 0.f, 0.f};
                #pragma unroll
                for (int kt = 0; kt < 3; ++kt)
                    acc = mf2(a0[rtl * 3 + kt], bh[kt], bl[kt], acc);
                int rowb = 16 * (2 * wv + rtl) + 4 * qq;   // 128..255
                if (nn < 2) *(fx4*)&sm.accL0[nn][rowb] = acc;
            }
        } else if (tid < 128) {
            int b = tid >> 6, i = tid & 63;
            float y = sm.yb[b][i];
            float acc8[8];
            #pragma unroll
            for (int d = 0; d < 8; ++d) acc8[d] = sm.roW[d][i] * y;
            #pragma unroll
            for (int m = 1; m < 64; m <<= 1) {
                #pragma unroll
                for (int d = 0; d < 8; ++d) acc8[d] += __shfl_xor(acc8[d], m);
            }
            if (i == 0) {
                float v8[8];
                #pragma unroll
                for (int d = 0; d < 8; ++d) v8[d] = acc8[d] + sm.rob[d];
                write_out<IS32>(out, (size_t)(bid * BB + b) * TPTS + s, v8);
            }
        } else if (tid >= 128 && tid < 136 && s + 1 < STEPS) {
            int q = tid - 128;
            if (IS32)       dwpref = ((const uint4*)dW)[(size_t)(s + 1) * 2048 + bid * 8 + q];
            else if (q < 4) dwpref = ((const uint4*)dW)[(size_t)(s + 1) * 1024 + bid * 4 + q];
        }
        __syncthreads();
        // PB2: activation diffusion L0 (256 thr)
        if (tid < 256) {
            int r = 128 + (tid >> 1), c = tid & 1;
            float h = lipswish(sm.accL0[c][r] + sm.b0s[r]);
            u16 hi, lo; split_bf(h, hi, lo);
            sm.bh1h[1][c][r - 128] = hi;
            sm.bh1l[1][c][r - 128] = lo;
        }
        __syncthreads();
        // PC2: diffusion L1 MFMA (waves 4-7)
        if (wv >= 4) {
            bf16x8 bh[4], bl[4];
            #pragma unroll
            for (int kt = 0; kt < 4; ++kt) {
                bh[kt] = bfrag(&sm.bh1h[1][nn & 1][32 * kt + 8 * qq]);
                bl[kt] = bfrag(&sm.bh1l[1][nn & 1][32 * kt + 8 * qq]);
            }
            int wl = wv & 3;
            #pragma unroll
            for (int rtl = 0; rtl < 2; ++rtl) {
                fx4 acc = {0.f, 0.f, 0.f, 0.f};
                #pragma unroll
                for (int kt = 0; kt < 4; ++kt)
                    acc = mf2(a1[rtl * 4 + kt], bh[kt], bl[kt], acc);
                int rowb = 128 + 16 * (2 * wl + rtl) + 4 * qq;
                if (nn < 2) *(fx4*)&sm.accL1[nn][rowb] = acc;
            }
        }
        __syncthreads();
        // PD2: activation diffusion L1 (256 thr)
        if (tid < 256) {
            int r = 128 + (tid >> 1), c = tid & 1;
            float h = lipswish(sm.accL1[c][r] + sm.b1s[r]);
            u16 hi, lo; split_bf(h, hi, lo);
            sm.bh2ch[c][r - 128] = hi;
            sm.bh2cl[c][r - 128] = lo;
        }
        __syncthreads();
        // PE2: big MFMA (all waves)
        {
            bf16x8 bh[4], bl[4];
            #pragma unroll
            for (int kt = 0; kt < 4; ++kt) {
                bh[kt] = bfrag(&sm.bh2ch[nn & 1][32 * kt + 8 * qq]);
                bl[kt] = bfrag(&sm.bh2cl[nn & 1][32 * kt + 8 * qq]);
            }
            #pragma unroll
            for (int r8 = 0; r8 < 8; ++r8) {
                fx4 acc = {0.f, 0.f, 0.f, 0.f};
                #pragma unroll
                for (int kt = 0; kt < 4; ++kt)
                    acc = mf2(ab[r8 * 4 + kt], bh[kt], bl[kt], acc);
                int rowb = 128 * wv + 16 * r8 + 4 * qq;
                if (nn < 2) *(fx4*)&sm.accBig[nn][rowb] = acc;
            }
        }
        __syncthreads();
        // PF2: g1, y1 update, pack next x (and t_{s+1})
        {
            int p = tid >> 2, q4 = tid & 3;
            int b = p >> 6, h = p & 63;
            int rb = 16 * h + 4 * q4;
            fx4 acc = *(const fx4*)&sm.accBig[b][rb];
            float4 cb = *(const float4*)&sm.cb2[rb];
            float4 cs = *(const float4*)&sm.csc[rb];
            float4 dw = *(const float4*)&sm.dwb[b][4 * q4];
            float v;
            v  = tanh_fast(acc.x + cb.x) * cs.x * dw.x;
            v  = fmaf(tanh_fast(acc.y + cb.y) * cs.y, dw.y, v);
            v  = fmaf(tanh_fast(acc.z + cb.z) * cs.z, dw.z, v);
            v  = fmaf(tanh_fast(acc.w + cb.w) * cs.w, dw.w, v);
            v += __shfl_xor(v, 1);
            v += __shfl_xor(v, 2);
            if (q4 == 0) {
                float y1 = sm.yb[b][h] + sm.fdt[b][h] + 0.5f * (sm.g0b[b][h] + v);
                sm.yb[b][h] = y1;
                u16 hi, lo; split_bf(y1, hi, lo);
                sm.bxh[b][1 + h] = hi; sm.bxl[b][1 + h] = lo;
                if (h == 0) {
                    u16 thi, tlo; split_bf(sm.tsb[s + 1], thi, tlo);
                    sm.bxh[b][0] = thi; sm.bxl[b][0] = tlo;
                }
            }
        }
        __syncthreads();
    }

    // final readout: y_1024 -> out[.., 1024]
    if (tid < 128) {
        int b = tid >> 6, i = tid & 63;
        float y = sm.yb[b][i];
        float acc8[8];
        #pragma unroll
        for (int d = 0; d < 8; ++d) acc8[d] = sm.roW[d][i] * y;
        #pragma unroll
        for (int m = 1; m < 64; m <<= 1) {
            #pragma unroll
            for (int d = 0; d < 8; ++d) acc8[d] += __shfl_xor(acc8[d], m);
        }
        if (i == 0) {
            float v8[8];
            #pragma unroll
            for (int d = 0; d < 8; ++d) v8[d] = acc8[d] + sm.rob[d];
            write_out<IS32>(out, (size_t)(bid * BB + b) * TPTS + STEPS, v8);
        }
    }
}

__global__ void
__attribute__((amdgpu_flat_work_group_size(NTHREADS, NTHREADS), amdgpu_waves_per_eu(2, 2)))
sde_kernel(const void* __restrict__ ts,  const void* __restrict__ z0,  const void* __restrict__ dW,
           const void* __restrict__ iW0, const void* __restrict__ ib0, const void* __restrict__ iW1,
           const void* __restrict__ ib1, const void* __restrict__ iW2, const void* __restrict__ ib2,
           const void* __restrict__ vW0, const void* __restrict__ vb0, const void* __restrict__ vW1,
           const void* __restrict__ vb1, const void* __restrict__ vW2, const void* __restrict__ vb2,
           const void* __restrict__ vsc, const void* __restrict__ cW0, const void* __restrict__ cb0,
           const void* __restrict__ cW1, const void* __restrict__ cb1, const void* __restrict__ cW2,
           const void* __restrict__ cb2, const void* __restrict__ csc, const void* __restrict__ roW,
           const void* __restrict__ rob, void* __restrict__ out)
{
    __shared__ SMem sm;
    const int tid = threadIdx.x;
    const int bid = blockIdx.x;

    // dtype detection: u16 word #1 of ts. bf16 array -> bf16(1/1024)=0x3A80 != 0;
    // fp32 array -> high half of 0.0f == 0.
    const bool is32 = (((const u16*)ts)[1] == 0);

    if (is32) {
        sde_run<true>(sm, ts, z0, dW, iW0, ib0, iW1, ib1, iW2, ib2,
                      vW0, vb0, vW1, vb1, vW2, vb2, vsc,
                      cW0, cb0, cW1, cb1, cW2, cb2, csc, roW, rob, out, tid, bid);
    } else {
        sde_run<false>(sm, ts, z0, dW, iW0, ib0, iW1, ib1, iW2, ib2,
                       vW0, vb0, vW1, vb1, vW2, vb2, vsc,
                       cW0, cb0, cW1, cb1, cW2, cb2, csc, roW, rob, out, tid, bid);
    }
}

extern "C" void kernel_launch(void* const* d_in, const int* in_sizes, int n_in,
                              void* d_out, int out_size, void* d_ws, size_t ws_size,
                              hipStream_t stream) {
    (void)in_sizes; (void)n_in; (void)d_ws; (void)ws_size; (void)out_size;
    hipLaunchKernelGGL(sde_kernel, dim3(NBLOCKS), dim3(NTHREADS), 0, stream,
                       d_in[0], d_in[1], d_in[2], d_in[3], d_in[4], d_in[5], d_in[6],
                       d_in[7], d_in[8], d_in[9], d_in[10], d_in[11], d_in[12], d_in[13],
                       d_in[14], d_in[15], d_in[16], d_in[17], d_in[18], d_in[19], d_in[20],
                       d_in[21], d_in[22], d_in[23], d_in[24], d_out);
}